// Round 1
// baseline (3763.211 us; speedup 1.0000x reference)
//
#include <hip/hip_runtime.h>
#include <hip/hip_bf16.h>

#define RREL 8
#define NB 20

static inline int cdiv(long a, long b){ return (int)((a + b - 1)/b); }

__device__ inline void atomAddF(float* p, float v){ unsafeAtomicAdd(p, v); }

__device__ inline void atomicMaxF(float* a, float v){
  if (v >= 0.f) atomicMax((int*)a, __float_as_int(v));
  else          atomicMin((unsigned int*)a, (unsigned int)__float_as_int(v));
}

// W[r,i,o] = sum_b comp[r,b] * basis[b,i,o];  8*128*128 outputs
__global__ __launch_bounds__(256) void k_relweights(const float* __restrict__ comp,
                                                    const float* __restrict__ basis,
                                                    float* __restrict__ W) {
  int idx = blockIdx.x*256 + threadIdx.x;   // r*16384 + io
  int r = idx >> 14, io = idx & 16383;
  float s = 0.f;
  #pragma unroll
  for (int b = 0; b < NB; ++b) s += comp[r*NB + b] * basis[b*16384 + io];
  W[idx] = s;
}

__global__ __launch_bounds__(256) void k_count(const int* __restrict__ dst,
                                               const int* __restrict__ et,
                                               int* __restrict__ cnt, int E) {
  int e = blockIdx.x*256 + threadIdx.x;
  if (e < E) atomicAdd(&cnt[dst[e]*RREL + et[e]], 1);
}

// Generic C[M,128] (+)= rowscale(A)[M,128] @ B[128,128]  (+ bias)
__global__ __launch_bounds__(256) void gemm_nk128(
    const float* __restrict__ A, const float* __restrict__ B,
    float* __restrict__ C, int M,
    const float* __restrict__ bias, const int* __restrict__ cnt, int rel, int accum)
{
  __shared__ float As[128][36];   // transposed [k][row], padded
  __shared__ float Bs[32][128];
  int t = threadIdx.x;
  int row0 = blockIdx.x * 32;

  for (int i = t; i < 32*128; i += 256) {
    int rr = i >> 7, k = i & 127;
    int row = row0 + rr;
    float v = 0.f;
    if (row < M) {
      v = A[(long)row*128 + k];
      if (cnt) {
        int c = cnt[row*RREL + rel];
        v *= (c > 0) ? (1.f/(float)c) : 0.f;   // mean; ssum row is 0 when c==0
      }
    }
    As[k][rr] = v;
  }

  float acc[4][4] = {};
  int tx = t & 31, ty = t >> 5;   // cols tx*4..+3, rows ty*4..+3

  for (int kc = 0; kc < 4; ++kc) {
    __syncthreads();
    for (int i = t; i < 32*128; i += 256) {
      int kk = i >> 7, col = i & 127;
      Bs[kk][col] = B[(kc*32 + kk)*128 + col];
    }
    __syncthreads();
    #pragma unroll
    for (int kk = 0; kk < 32; ++kk) {
      float4 a = *(const float4*)&As[kc*32 + kk][ty*4];
      float4 b = *(const float4*)&Bs[kk][tx*4];
      acc[0][0] += a.x*b.x; acc[0][1] += a.x*b.y; acc[0][2] += a.x*b.z; acc[0][3] += a.x*b.w;
      acc[1][0] += a.y*b.x; acc[1][1] += a.y*b.y; acc[1][2] += a.y*b.z; acc[1][3] += a.y*b.w;
      acc[2][0] += a.z*b.x; acc[2][1] += a.z*b.y; acc[2][2] += a.z*b.z; acc[2][3] += a.z*b.w;
      acc[3][0] += a.w*b.x; acc[3][1] += a.w*b.y; acc[3][2] += a.w*b.z; acc[3][3] += a.w*b.w;
    }
  }

  #pragma unroll
  for (int i = 0; i < 4; ++i) {
    int row = row0 + ty*4 + i;
    if (row >= M) continue;
    #pragma unroll
    for (int j = 0; j < 4; ++j) {
      int col = tx*4 + j;
      float v = acc[i][j];
      if (bias) v += bias[col];
      float* p = &C[(long)row*128 + col];
      if (accum) *p += v; else *p = v;
    }
  }
}

// ssum[dst] += x[src] for edges of relation rel; 32 lanes per edge (float4 each)
__global__ __launch_bounds__(256) void k_scatter(const int* __restrict__ src,
    const int* __restrict__ dst, const int* __restrict__ et,
    const float* __restrict__ x, float* __restrict__ ssum, int rel, int E)
{
  int g = (blockIdx.x*256 + threadIdx.x) >> 5;
  if (g >= E) return;
  if (et[g] != rel) return;
  int l = threadIdx.x & 31;
  int s = src[g], d = dst[g];
  float4 v = ((const float4*)x)[(long)s*32 + l];
  float* o = ssum + (long)d*128 + l*4;
  atomAddF(o+0, v.x); atomAddF(o+1, v.y); atomAddF(o+2, v.z); atomAddF(o+3, v.w);
}

// a_src/a_dst[n,h] = sum_k xl[n,h,k]*att[h,k]
__global__ __launch_bounds__(256) void k_att(const float* __restrict__ xl,
    const float* __restrict__ attS, const float* __restrict__ attD,
    float* __restrict__ aS, float* __restrict__ aD, int Nn)
{
  int idx = blockIdx.x*256 + threadIdx.x;
  if (idx >= Nn*4) return;
  int n = idx >> 2, h = idx & 3;
  const float* xr = xl + (long)n*128 + h*32;
  float s1 = 0.f, s2 = 0.f;
  #pragma unroll
  for (int k = 0; k < 32; ++k) { float v = xr[k]; s1 += v*attS[h*32+k]; s2 += v*attD[h*32+k]; }
  aS[idx] = s1; aD[idx] = s2;
}

__global__ __launch_bounds__(256) void k_initm(float* __restrict__ m, int n){
  int i = blockIdx.x*256 + threadIdx.x;
  if (i < n) m[i] = __int_as_float(0xff800000);  // -inf
}

__global__ __launch_bounds__(256) void k_gat_max(const int* __restrict__ src,
    const int* __restrict__ dst, const float* __restrict__ aS,
    const float* __restrict__ aD, float* __restrict__ m, int E, int Nn)
{
  int i = blockIdx.x*256 + threadIdx.x;
  if (i >= E + Nn) return;
  int s, d;
  if (i < E) { s = src[i]; d = dst[i]; if (s == d) return; }
  else { s = d = i - E; }
  float4 as4 = ((const float4*)aS)[s];
  float4 ad4 = ((const float4*)aD)[d];
  float al0 = as4.x + ad4.x, al1 = as4.y + ad4.y, al2 = as4.z + ad4.z, al3 = as4.w + ad4.w;
  al0 = al0 > 0.f ? al0 : 0.2f*al0;  al1 = al1 > 0.f ? al1 : 0.2f*al1;
  al2 = al2 > 0.f ? al2 : 0.2f*al2;  al3 = al3 > 0.f ? al3 : 0.2f*al3;
  atomicMaxF(&m[d*4+0], al0); atomicMaxF(&m[d*4+1], al1);
  atomicMaxF(&m[d*4+2], al2); atomicMaxF(&m[d*4+3], al3);
}

// fused: denom[d,h] += e^(alpha-m);  out[d,:] += xl[s,:]*e^(alpha-m)
__global__ __launch_bounds__(256) void k_gat_acc(const int* __restrict__ src,
    const int* __restrict__ dst, const float* __restrict__ aS,
    const float* __restrict__ aD, const float* __restrict__ m,
    const float* __restrict__ xl, float* __restrict__ den,
    float* __restrict__ out, int E, int Nn)
{
  int g = (blockIdx.x*256 + threadIdx.x) >> 5;
  if (g >= E + Nn) return;
  int s, d;
  if (g < E) { s = src[g]; d = dst[g]; if (s == d) return; }
  else { s = d = g - E; }
  int l = threadIdx.x & 31;
  int h = l >> 3;
  float al = aS[s*4+h] + aD[d*4+h];
  al = al > 0.f ? al : 0.2f*al;
  float w = __expf(al - m[d*4+h]);
  if ((l & 7) == 0) atomAddF(&den[d*4+h], w);
  float4 v = ((const float4*)xl)[(long)s*32 + l];
  float* o = out + (long)d*128 + l*4;
  atomAddF(o+0, v.x*w); atomAddF(o+1, v.y*w); atomAddF(o+2, v.z*w); atomAddF(o+3, v.w*w);
}

__global__ __launch_bounds__(256) void k_final(float* __restrict__ out,
    const float* __restrict__ den, const float* __restrict__ gatb, int Nn)
{
  int idx = blockIdx.x*256 + threadIdx.x;
  if (idx >= Nn*128) return;
  int n = idx >> 7, c = idx & 127;
  out[idx] = out[idx] / den[n*4 + (c >> 5)] + gatb[c];
}

extern "C" void kernel_launch(void* const* d_in, const int* in_sizes, int n_in,
                              void* d_out, int out_size, void* d_ws, size_t ws_size,
                              hipStream_t stream) {
  const float* x     = (const float*)d_in[0];
  const int*   eidx  = (const int*)  d_in[1];
  const int*   etype = (const int*)  d_in[2];
  const float* comp  = (const float*)d_in[3];
  const float* basis = (const float*)d_in[4];
  const float* root  = (const float*)d_in[5];
  const float* bias1 = (const float*)d_in[6];
  const float* gatw  = (const float*)d_in[7];
  const float* attS  = (const float*)d_in[8];
  const float* attD  = (const float*)d_in[9];
  const float* gatb  = (const float*)d_in[10];

  int Nn = in_sizes[0] / 128;
  int E  = in_sizes[2];
  const int* src = eidx;
  const int* dst = eidx + E;

  char* ws = (char*)d_ws;
  size_t o = 0;
  float* W    = (float*)(ws + o); o += (size_t)RREL*128*128*4;   // 512 KB
  float* h    = (float*)(ws + o); o += (size_t)Nn*128*4;
  float* ssum = (float*)(ws + o); o += (size_t)Nn*128*4;
  float* xl   = (float*)(ws + o); o += (size_t)Nn*128*4;
  int*   cnt  = (int*)  (ws + o); o += (size_t)Nn*RREL*4;
  float* aS   = (float*)(ws + o); o += (size_t)Nn*4*4;
  float* aD   = (float*)(ws + o); o += (size_t)Nn*4*4;
  float* m    = (float*)(ws + o); o += (size_t)Nn*4*4;
  float* den  = (float*)(ws + o); o += (size_t)Nn*4*4;

  float* out = (float*)d_out;

  hipMemsetAsync(cnt, 0, (size_t)Nn*RREL*4, stream);
  hipMemsetAsync(den, 0, (size_t)Nn*4*4, stream);
  hipMemsetAsync(out, 0, (size_t)Nn*128*4, stream);

  k_relweights<<<512, 256, 0, stream>>>(comp, basis, W);
  k_count<<<cdiv(E,256), 256, 0, stream>>>(dst, etype, cnt, E);
  // h = x @ root + bias1
  gemm_nk128<<<cdiv(Nn,32), 256, 0, stream>>>(x, root, h, Nn, bias1, nullptr, 0, 0);
  // h += mean_r @ W[r]
  for (int r = 0; r < RREL; ++r) {
    hipMemsetAsync(ssum, 0, (size_t)Nn*128*4, stream);
    k_scatter<<<cdiv((long)E*32,256), 256, 0, stream>>>(src, dst, etype, x, ssum, r, E);
    gemm_nk128<<<cdiv(Nn,32), 256, 0, stream>>>(ssum, W + (size_t)r*16384, h, Nn, nullptr, cnt, r, 1);
  }
  // GAT
  gemm_nk128<<<cdiv(Nn,32), 256, 0, stream>>>(h, gatw, xl, Nn, nullptr, nullptr, 0, 0);
  k_att<<<cdiv((long)Nn*4,256), 256, 0, stream>>>(xl, attS, attD, aS, aD, Nn);
  k_initm<<<cdiv((long)Nn*4,256), 256, 0, stream>>>(m, Nn*4);
  k_gat_max<<<cdiv((long)E+Nn,256), 256, 0, stream>>>(src, dst, aS, aD, m, E, Nn);
  k_gat_acc<<<cdiv(((long)E+Nn)*32,256), 256, 0, stream>>>(src, dst, aS, aD, m, xl, den, out, E, Nn);
  k_final<<<cdiv((long)Nn*128,256), 256, 0, stream>>>(out, den, gatb, Nn);
}

// Round 2
// 1624.721 us; speedup vs baseline: 2.3162x; 2.3162x over previous
//
#include <hip/hip_runtime.h>
#include <hip/hip_bf16.h>

#define RREL 8
#define NB 20
#define SELFBIT (1u<<19)

static inline int cdiv(long a, long b){ return (int)((a + b - 1)/b); }

// W[r,i,o] = sum_b comp[r,b] * basis[b,i,o];  stored flat [1024][128]
__global__ __launch_bounds__(256) void k_relweights(const float* __restrict__ comp,
                                                    const float* __restrict__ basis,
                                                    float* __restrict__ W) {
  int idx = blockIdx.x*256 + threadIdx.x;   // r*16384 + io
  int r = idx >> 14, io = idx & 16383;
  float s = 0.f;
  #pragma unroll
  for (int b = 0; b < NB; ++b) s += comp[r*NB + b] * basis[b*16384 + io];
  W[idx] = s;
}

__global__ __launch_bounds__(256) void k_hist(const int* __restrict__ dst,
                                              int* __restrict__ deg, int E) {
  int e = blockIdx.x*256 + threadIdx.x;
  if (e < E) atomicAdd(&deg[dst[e]], 1);
}

// exclusive scan of deg -> ofs and cur (single block, 1024 threads)
__global__ __launch_bounds__(1024) void k_scan(const int* __restrict__ deg,
    int* __restrict__ ofs, int* __restrict__ cur, int Nn)
{
  __shared__ int wsum[17];
  __shared__ int base_s;
  int t = threadIdx.x, lane = t & 63, wv = t >> 6;
  if (t == 0) base_s = 0;
  __syncthreads();
  for (int c0 = 0; c0 < Nn; c0 += 1024) {
    int i = c0 + t;
    int v = (i < Nn) ? deg[i] : 0;
    int incl = v;
    #pragma unroll
    for (int d = 1; d < 64; d <<= 1) {
      int u = __shfl_up(incl, d);
      if (lane >= d) incl += u;
    }
    if (lane == 63) wsum[wv] = incl;
    __syncthreads();
    if (t == 0) {
      int run = 0;
      #pragma unroll
      for (int k2 = 0; k2 < 16; ++k2) { int s2 = wsum[k2]; wsum[k2] = run; run += s2; }
      wsum[16] = run;
    }
    __syncthreads();
    int base = base_s;
    int excl = base + wsum[wv] + incl - v;
    if (i < Nn) { ofs[i] = excl; cur[i] = excl; }
    __syncthreads();
    if (t == 0) base_s = base + wsum[16];
    __syncthreads();
  }
}

__global__ __launch_bounds__(256) void k_permute(const int* __restrict__ src,
    const int* __restrict__ dst, const int* __restrict__ et,
    int* __restrict__ cur, unsigned* __restrict__ packed, int E)
{
  int e = blockIdx.x*256 + threadIdx.x;
  if (e >= E) return;
  int d = dst[e], s = src[e], r = et[e];
  int p = atomicAdd(&cur[d], 1);
  unsigned w = (unsigned)s | ((unsigned)r << 16) | ((s == d) ? SELFBIT : 0u);
  packed[p] = w;
}

// C[M,128] (+)= A[M,128] @ B[128,128] (+ bias)
__global__ __launch_bounds__(256) void gemm_nk128(
    const float* __restrict__ A, const float* __restrict__ B,
    float* __restrict__ C, int M, const float* __restrict__ bias, int accum)
{
  __shared__ float As[128][36];   // [k][row], padded
  __shared__ float Bs[32][128];
  int t = threadIdx.x;
  int row0 = blockIdx.x * 32;

  for (int i = t; i < 32*128; i += 256) {
    int rr = i >> 7, k = i & 127;
    int row = row0 + rr;
    As[k][rr] = (row < M) ? A[(long)row*128 + k] : 0.f;
  }

  float acc[4][4] = {};
  int tx = t & 31, ty = t >> 5;

  for (int kc = 0; kc < 4; ++kc) {
    __syncthreads();
    for (int i = t; i < 32*128; i += 256) {
      int kk = i >> 7, col = i & 127;
      Bs[kk][col] = B[(kc*32 + kk)*128 + col];
    }
    __syncthreads();
    #pragma unroll
    for (int kk = 0; kk < 32; ++kk) {
      float4 a = *(const float4*)&As[kc*32 + kk][ty*4];
      float4 b = *(const float4*)&Bs[kk][tx*4];
      acc[0][0] += a.x*b.x; acc[0][1] += a.x*b.y; acc[0][2] += a.x*b.z; acc[0][3] += a.x*b.w;
      acc[1][0] += a.y*b.x; acc[1][1] += a.y*b.y; acc[1][2] += a.y*b.z; acc[1][3] += a.y*b.w;
      acc[2][0] += a.z*b.x; acc[2][1] += a.z*b.y; acc[2][2] += a.z*b.z; acc[2][3] += a.z*b.w;
      acc[3][0] += a.w*b.x; acc[3][1] += a.w*b.y; acc[3][2] += a.w*b.z; acc[3][3] += a.w*b.w;
    }
  }

  #pragma unroll
  for (int i = 0; i < 4; ++i) {
    int row = row0 + ty*4 + i;
    if (row >= M) continue;
    #pragma unroll
    for (int j = 0; j < 4; ++j) {
      int col = tx*4 + j;
      float v = acc[i][j];
      if (bias) v += bias[col];
      float* p = &C[(long)row*128 + col];
      if (accum) *p += v; else *p = v;
    }
  }
}

// Fused RGCN: per-node per-relation mean aggregation (registers->LDS) + S@W GEMM
#define NPB 16
__global__ __launch_bounds__(256) void k_rgcn(const unsigned* __restrict__ packed,
    const int* __restrict__ ofs, const int* __restrict__ deg,
    const float* __restrict__ x, const float* __restrict__ W,
    float* __restrict__ h, int Nn)
{
  __shared__ float S[NPB][1024];
  __shared__ float Bs[32][128];
  int t = threadIdx.x, lane = t & 63, wv = t >> 6;
  int n0 = blockIdx.x * NPB;

  // phase 1: each wave aggregates 4 nodes; acc[rel][2ch] in registers
  for (int ni = 0; ni < 4; ++ni) {
    int n = n0 + wv*4 + ni;
    float acc[RREL][2] = {};
    int cnt[RREL] = {};
    if (n < Nn) {
      int o = ofs[n], dg = deg[n];
      unsigned pkc = 0; float2 vc = {0.f, 0.f};
      if (dg > 0) {
        pkc = packed[o];
        vc = *(const float2*)&x[(long)(pkc & 0xFFFF)*128 + lane*2];
      }
      for (int e = 0; e < dg; ++e) {
        unsigned pkn = 0; float2 vn = {0.f, 0.f};
        if (e + 1 < dg) {
          pkn = packed[o + e + 1];
          vn = *(const float2*)&x[(long)(pkn & 0xFFFF)*128 + lane*2];
        }
        int r = (pkc >> 16) & 7;
        #pragma unroll
        for (int rr = 0; rr < RREL; ++rr) {
          bool msk = (r == rr);
          cnt[rr] += msk;
          float f = msk ? 1.f : 0.f;
          acc[rr][0] = fmaf(f, vc.x, acc[rr][0]);
          acc[rr][1] = fmaf(f, vc.y, acc[rr][1]);
        }
        pkc = pkn; vc = vn;
      }
    }
    int nl = wv*4 + ni;
    #pragma unroll
    for (int rr = 0; rr < RREL; ++rr) {
      float inv = (cnt[rr] > 0) ? 1.f/(float)cnt[rr] : 0.f;
      S[nl][rr*128 + lane*2]     = acc[rr][0]*inv;
      S[nl][rr*128 + lane*2 + 1] = acc[rr][1]*inv;
    }
  }
  __syncthreads();

  // phase 2: h[n0+row][col] += sum_k S[row][k]*W[k*128+col]
  int tx = t & 31, ty = t >> 5;   // tx: 4 cols; ty: 2 rows
  float acc2[2][4] = {};
  for (int kc = 0; kc < 32; ++kc) {
    for (int i = t; i < 4096; i += 256) {
      int kk = i >> 7, col = i & 127;
      Bs[kk][col] = W[(kc*32 + kk)*128 + col];
    }
    __syncthreads();
    #pragma unroll
    for (int kk = 0; kk < 32; ++kk) {
      int k = kc*32 + kk;
      float a0 = S[ty*2 + 0][k];
      float a1 = S[ty*2 + 1][k];
      float4 b = *(const float4*)&Bs[kk][tx*4];
      acc2[0][0] += a0*b.x; acc2[0][1] += a0*b.y; acc2[0][2] += a0*b.z; acc2[0][3] += a0*b.w;
      acc2[1][0] += a1*b.x; acc2[1][1] += a1*b.y; acc2[1][2] += a1*b.z; acc2[1][3] += a1*b.w;
    }
    __syncthreads();
  }
  #pragma unroll
  for (int i = 0; i < 2; ++i) {
    int n = n0 + ty*2 + i;
    if (n >= Nn) continue;
    #pragma unroll
    for (int j = 0; j < 4; ++j)
      h[(long)n*128 + tx*4 + j] += acc2[i][j];
  }
}

// a_src/a_dst[n,h] = sum_k xl[n,h,k]*att[h,k]
__global__ __launch_bounds__(256) void k_att(const float* __restrict__ xl,
    const float* __restrict__ attS, const float* __restrict__ attD,
    float* __restrict__ aS, float* __restrict__ aD, int Nn)
{
  int idx = blockIdx.x*256 + threadIdx.x;
  if (idx >= Nn*4) return;
  int n = idx >> 2, h = idx & 3;
  const float* xr = xl + (long)n*128 + h*32;
  float s1 = 0.f, s2 = 0.f;
  #pragma unroll
  for (int k = 0; k < 32; ++k) { float v = xr[k]; s1 += v*attS[h*32+k]; s2 += v*attD[h*32+k]; }
  aS[idx] = s1; aD[idx] = s2;
}

__device__ inline float lrelu(float v){ return v > 0.f ? v : 0.2f*v; }

// GAT: wave per destination node, two-pass softmax over CSR edges + self-loop
__global__ __launch_bounds__(256) void k_gat(const unsigned* __restrict__ packed,
    const int* __restrict__ ofs, const int* __restrict__ deg,
    const float* __restrict__ aS, const float* __restrict__ aD,
    const float* __restrict__ xl, const float* __restrict__ gatb,
    float* __restrict__ out, int Nn)
{
  int n = (blockIdx.x*256 + threadIdx.x) >> 6;
  if (n >= Nn) return;
  int lane = threadIdx.x & 63;
  int o = ofs[n], dg = deg[n];

  float4 aD4 = *(const float4*)&aD[(long)n*4];
  float4 aS4 = *(const float4*)&aS[(long)n*4];
  float sl0 = lrelu(aS4.x + aD4.x), sl1 = lrelu(aS4.y + aD4.y);
  float sl2 = lrelu(aS4.z + aD4.z), sl3 = lrelu(aS4.w + aD4.w);

  // pass A: per-head max (lane-parallel over edges)
  float m0 = sl0, m1 = sl1, m2 = sl2, m3 = sl3;
  for (int e = lane; e < dg; e += 64) {
    unsigned pk = packed[o + e];
    if (pk & SELFBIT) continue;
    int s = pk & 0xFFFF;
    float4 a = *(const float4*)&aS[(long)s*4];
    m0 = fmaxf(m0, lrelu(a.x + aD4.x));
    m1 = fmaxf(m1, lrelu(a.y + aD4.y));
    m2 = fmaxf(m2, lrelu(a.z + aD4.z));
    m3 = fmaxf(m3, lrelu(a.w + aD4.w));
  }
  #pragma unroll
  for (int d = 1; d < 64; d <<= 1) {
    m0 = fmaxf(m0, __shfl_xor(m0, d));
    m1 = fmaxf(m1, __shfl_xor(m1, d));
    m2 = fmaxf(m2, __shfl_xor(m2, d));
    m3 = fmaxf(m3, __shfl_xor(m3, d));
  }

  // pass B: lane handles channels 2*lane, 2*lane+1; head = lane>>4
  int hh = lane >> 4;
  float mh   = hh == 0 ? m0  : hh == 1 ? m1  : hh == 2 ? m2  : m3;
  float aDnh = hh == 0 ? aD4.x : hh == 1 ? aD4.y : hh == 2 ? aD4.z : aD4.w;
  float slh  = hh == 0 ? sl0 : hh == 1 ? sl1 : hh == 2 ? sl2 : sl3;

  float wself = __expf(slh - mh);
  float den = wself;
  float2 xs = *(const float2*)&xl[(long)n*128 + lane*2];
  float acc0 = xs.x * wself, acc1 = xs.y * wself;

  unsigned pkc = (dg > 0) ? packed[o] : 0u;
  for (int e = 0; e < dg; ++e) {
    unsigned pkn = (e + 1 < dg) ? packed[o + e + 1] : 0u;
    if (!(pkc & SELFBIT)) {
      int s = pkc & 0xFFFF;
      float al = lrelu(aS[(long)s*4 + hh] + aDnh);
      float wgt = __expf(al - mh);
      den += wgt;
      float2 v = *(const float2*)&xl[(long)s*128 + lane*2];
      acc0 = fmaf(v.x, wgt, acc0);
      acc1 = fmaf(v.y, wgt, acc1);
    }
    pkc = pkn;
  }
  float2 r;
  r.x = acc0/den + gatb[lane*2];
  r.y = acc1/den + gatb[lane*2 + 1];
  *(float2*)&out[(long)n*128 + lane*2] = r;
}

extern "C" void kernel_launch(void* const* d_in, const int* in_sizes, int n_in,
                              void* d_out, int out_size, void* d_ws, size_t ws_size,
                              hipStream_t stream) {
  const float* x     = (const float*)d_in[0];
  const int*   eidx  = (const int*)  d_in[1];
  const int*   etype = (const int*)  d_in[2];
  const float* comp  = (const float*)d_in[3];
  const float* basis = (const float*)d_in[4];
  const float* root  = (const float*)d_in[5];
  const float* bias1 = (const float*)d_in[6];
  const float* gatw  = (const float*)d_in[7];
  const float* attS  = (const float*)d_in[8];
  const float* attD  = (const float*)d_in[9];
  const float* gatb  = (const float*)d_in[10];

  int Nn = in_sizes[0] / 128;
  int E  = in_sizes[2];
  const int* src = eidx;
  const int* dst = eidx + E;

  char* ws = (char*)d_ws;
  size_t o = 0;
  float* W    = (float*)(ws + o); o += (size_t)RREL*128*128*4;   // [1024][128]
  float* h    = (float*)(ws + o); o += (size_t)Nn*128*4;
  float* xl   = (float*)(ws + o); o += (size_t)Nn*128*4;
  float* aS   = (float*)(ws + o); o += (size_t)Nn*4*4;
  float* aD   = (float*)(ws + o); o += (size_t)Nn*4*4;
  int*   deg  = (int*)  (ws + o); o += (size_t)Nn*4;
  int*   ofs  = (int*)  (ws + o); o += (size_t)Nn*4;
  int*   cur  = (int*)  (ws + o); o += (size_t)Nn*4;
  unsigned* packed = (unsigned*)(ws + o); o += (size_t)E*4;

  float* out = (float*)d_out;

  hipMemsetAsync(deg, 0, (size_t)Nn*4, stream);

  k_relweights<<<512, 256, 0, stream>>>(comp, basis, W);
  k_hist<<<cdiv(E,256), 256, 0, stream>>>(dst, deg, E);
  k_scan<<<1, 1024, 0, stream>>>(deg, ofs, cur, Nn);
  k_permute<<<cdiv(E,256), 256, 0, stream>>>(src, dst, etype, cur, packed, E);

  // h = x @ root + bias1
  gemm_nk128<<<cdiv(Nn,32), 256, 0, stream>>>(x, root, h, Nn, bias1, 0);
  // h += sum_r mean_r @ W[r]   (fused aggregation + GEMM)
  k_rgcn<<<cdiv(Nn,NPB), 256, 0, stream>>>(packed, ofs, deg, x, W, h, Nn);

  // GAT
  gemm_nk128<<<cdiv(Nn,32), 256, 0, stream>>>(h, gatw, xl, Nn, nullptr, 0);
  k_att<<<cdiv((long)Nn*4,256), 256, 0, stream>>>(xl, attS, attD, aS, aD, Nn);
  k_gat<<<cdiv(Nn,4), 256, 0, stream>>>(packed, ofs, deg, aS, aD, xl, gatb, out, Nn);
}

// Round 3
// 631.051 us; speedup vs baseline: 5.9634x; 2.5746x over previous
//
#include <hip/hip_runtime.h>
#include <hip/hip_bf16.h>

#define RREL 8
#define NB 20
#define SELFBIT (1u<<19)

static inline int cdiv(long a, long b){ return (int)((a + b - 1)/b); }

// W[r,i,o] = sum_b comp[r,b]*basis[b,i,o]; flat [k=r*128+i][o]
__global__ __launch_bounds__(256) void k_relweights(const float* __restrict__ comp,
    const float* __restrict__ basis, float* __restrict__ W) {
  int idx = blockIdx.x*256 + threadIdx.x;
  int r = idx >> 14, io = idx & 16383;
  float s = 0.f;
  #pragma unroll
  for (int b = 0; b < NB; ++b) s += comp[r*NB + b] * basis[b*16384 + io];
  W[idx] = s;
}

__global__ __launch_bounds__(256) void k_hist(const int* __restrict__ dst,
    const int* __restrict__ et, int* __restrict__ deg, int* __restrict__ cnt8, int E) {
  int e = blockIdx.x*256 + threadIdx.x;
  if (e < E) { int d = dst[e]; atomicAdd(&deg[d], 1); atomicAdd(&cnt8[d*8 + et[e]], 1); }
}

// exclusive scan of deg -> ofs and cur (single block, 1024 threads)
__global__ __launch_bounds__(1024) void k_scan(const int* __restrict__ deg,
    int* __restrict__ ofs, int* __restrict__ cur, int Nn)
{
  __shared__ int wsum[17];
  __shared__ int base_s;
  int t = threadIdx.x, lane = t & 63, wv = t >> 6;
  if (t == 0) base_s = 0;
  __syncthreads();
  for (int c0 = 0; c0 < Nn; c0 += 1024) {
    int i = c0 + t;
    int v = (i < Nn) ? deg[i] : 0;
    int incl = v;
    #pragma unroll
    for (int d = 1; d < 64; d <<= 1) {
      int u = __shfl_up(incl, d);
      if (lane >= d) incl += u;
    }
    if (lane == 63) wsum[wv] = incl;
    __syncthreads();
    if (t == 0) {
      int run = 0;
      #pragma unroll
      for (int k2 = 0; k2 < 16; ++k2) { int s2 = wsum[k2]; wsum[k2] = run; run += s2; }
      wsum[16] = run;
    }
    __syncthreads();
    int base = base_s;
    int excl = base + wsum[wv] + incl - v;
    if (i < Nn) { ofs[i] = excl; cur[i] = excl; }
    __syncthreads();
    if (t == 0) base_s = base + wsum[16];
    __syncthreads();
  }
}

__global__ __launch_bounds__(256) void k_permute(const int* __restrict__ src,
    const int* __restrict__ dst, const int* __restrict__ et,
    const int* __restrict__ cnt8, int* __restrict__ cur,
    unsigned* __restrict__ packed, int E)
{
  int e = blockIdx.x*256 + threadIdx.x;
  if (e >= E) return;
  int d = dst[e], s = src[e], r = et[e];
  int p = atomicAdd(&cur[d], 1);
  unsigned c = (unsigned)cnt8[d*8 + r];
  packed[p] = (unsigned)s | ((unsigned)r << 16) | ((s == d) ? SELFBIT : 0u) | (c << 20);
}

// C[M,128] (+)= A[M,K] @ B[K,128] (+bias), K % 32 == 0
__global__ __launch_bounds__(256) void gemm128(const float* __restrict__ A,
    const float* __restrict__ B, float* __restrict__ C, int M, int K,
    const float* __restrict__ bias, int accum)
{
  __shared__ float As[32][36];   // [k][row] transposed
  __shared__ float Bs[32][128];
  int t = threadIdx.x;
  int row0 = blockIdx.x * 32;
  int tx = t & 31, ty = t >> 5;
  int arow = t >> 3, akq = (t & 7) * 4;
  float acc[4][4] = {};

  for (int kc = 0; kc < K; kc += 32) {
    int row = row0 + arow;
    float4 av = (row < M) ? *(const float4*)&A[(long)row*K + kc + akq]
                          : make_float4(0.f,0.f,0.f,0.f);
    As[akq+0][arow] = av.x; As[akq+1][arow] = av.y;
    As[akq+2][arow] = av.z; As[akq+3][arow] = av.w;
    #pragma unroll
    for (int q = 0; q < 4; ++q) {
      int kk = ty + q*8;
      *(float4*)&Bs[kk][tx*4] = *(const float4*)&B[(long)(kc+kk)*128 + tx*4];
    }
    __syncthreads();
    #pragma unroll
    for (int kk = 0; kk < 32; ++kk) {
      float4 a = *(const float4*)&As[kk][ty*4];
      float4 b = *(const float4*)&Bs[kk][tx*4];
      acc[0][0] += a.x*b.x; acc[0][1] += a.x*b.y; acc[0][2] += a.x*b.z; acc[0][3] += a.x*b.w;
      acc[1][0] += a.y*b.x; acc[1][1] += a.y*b.y; acc[1][2] += a.y*b.z; acc[1][3] += a.y*b.w;
      acc[2][0] += a.z*b.x; acc[2][1] += a.z*b.y; acc[2][2] += a.z*b.z; acc[2][3] += a.z*b.w;
      acc[3][0] += a.w*b.x; acc[3][1] += a.w*b.y; acc[3][2] += a.w*b.z; acc[3][3] += a.w*b.w;
    }
    __syncthreads();
  }

  #pragma unroll
  for (int i = 0; i < 4; ++i) {
    int row = row0 + ty*4 + i;
    if (row >= M) continue;
    #pragma unroll
    for (int j = 0; j < 4; ++j) {
      int col = tx*4 + j;
      float v = acc[i][j];
      if (bias) v += bias[col];
      float* p = &C[(long)row*128 + col];
      if (accum) *p += v; else *p = v;
    }
  }
}

// Fused RGCN: batched per-node scaled aggregation (regs -> bf16 LDS) + S@W GEMM
#define NPB 16
__global__ __launch_bounds__(256) void k_rgcn(const unsigned* __restrict__ packed,
    const int* __restrict__ ofs, const int* __restrict__ deg,
    const float* __restrict__ x, const float* __restrict__ W,
    float* __restrict__ h, int Nn)
{
  __shared__ __hip_bfloat16 S[NPB][1024];   // 32 KB
  __shared__ float Bs[32][128];             // 16 KB
  int t = threadIdx.x, lane = t & 63, wv = t >> 6;
  int n0 = blockIdx.x * NPB;

  // phase 1: each wave aggregates 4 nodes, 4-deep edge pipeline
  for (int ni = 0; ni < 4; ++ni) {
    int n = n0 + wv*4 + ni;
    float a0[RREL] = {}, a1[RREL] = {};
    if (n < Nn) {
      int o = ofs[n], dg = deg[n];
      for (int e0 = 0; e0 < dg; e0 += 4) {
        unsigned pk[4]; float2 v[4];
        #pragma unroll
        for (int j = 0; j < 4; ++j)
          pk[j] = (e0 + j < dg) ? packed[o + e0 + j] : (1u << 20);
        #pragma unroll
        for (int j = 0; j < 4; ++j) {
          int s = pk[j] & 0xFFFF;
          v[j] = *(const float2*)&x[(long)s*128 + lane*2];
        }
        #pragma unroll
        for (int j = 0; j < 4; ++j) {
          if (e0 + j < dg) {      // wave-uniform
            int r = (pk[j] >> 16) & 7;
            float sc = __builtin_amdgcn_rcpf((float)(pk[j] >> 20));
            float sx = v[j].x * sc, sy = v[j].y * sc;
            #pragma unroll
            for (int rr = 0; rr < RREL; ++rr) {
              float mk = (r == rr) ? 1.f : 0.f;
              a0[rr] = fmaf(mk, sx, a0[rr]);
              a1[rr] = fmaf(mk, sy, a1[rr]);
            }
          }
        }
      }
    }
    int nl = wv*4 + ni;
    #pragma unroll
    for (int rr = 0; rr < RREL; ++rr) {
      float2 f2; f2.x = a0[rr]; f2.y = a1[rr];
      *(__hip_bfloat162*)&S[nl][rr*128 + lane*2] = __float22bfloat162_rn(f2);
    }
  }
  __syncthreads();

  // phase 2: h[n0+row][col] += sum_k S[row][k] * W[k][col]
  int tx = t & 31, ty = t >> 5;   // rows ty*2+{0,1}, cols tx*4..+3
  float acc[2][4] = {};
  for (int kc = 0; kc < 32; ++kc) {
    #pragma unroll
    for (int q = 0; q < 4; ++q) {
      int kk = ty + q*8;
      *(float4*)&Bs[kk][tx*4] = *(const float4*)&W[(long)(kc*32 + kk)*128 + tx*4];
    }
    __syncthreads();
    #pragma unroll
    for (int kk = 0; kk < 32; kk += 2) {
      float2 s0 = __bfloat1622float2(*(const __hip_bfloat162*)&S[ty*2+0][kc*32 + kk]);
      float2 s1 = __bfloat1622float2(*(const __hip_bfloat162*)&S[ty*2+1][kc*32 + kk]);
      float4 b0 = *(const float4*)&Bs[kk][tx*4];
      float4 b1 = *(const float4*)&Bs[kk+1][tx*4];
      acc[0][0] += s0.x*b0.x; acc[0][1] += s0.x*b0.y; acc[0][2] += s0.x*b0.z; acc[0][3] += s0.x*b0.w;
      acc[0][0] += s0.y*b1.x; acc[0][1] += s0.y*b1.y; acc[0][2] += s0.y*b1.z; acc[0][3] += s0.y*b1.w;
      acc[1][0] += s1.x*b0.x; acc[1][1] += s1.x*b0.y; acc[1][2] += s1.x*b0.z; acc[1][3] += s1.x*b0.w;
      acc[1][0] += s1.y*b1.x; acc[1][1] += s1.y*b1.y; acc[1][2] += s1.y*b1.z; acc[1][3] += s1.y*b1.w;
    }
    __syncthreads();
  }
  #pragma unroll
  for (int i = 0; i < 2; ++i) {
    int row = n0 + ty*2 + i;
    if (row < Nn) {
      float4* hp = (float4*)&h[(long)row*128 + tx*4];
      float4 cv = *hp;
      cv.x += acc[i][0]; cv.y += acc[i][1]; cv.z += acc[i][2]; cv.w += acc[i][3];
      *hp = cv;
    }
  }
}

__global__ __launch_bounds__(256) void k_att(const float* __restrict__ xl,
    const float* __restrict__ attS, const float* __restrict__ attD,
    float* __restrict__ aS, float* __restrict__ aD, int Nn)
{
  int idx = blockIdx.x*256 + threadIdx.x;
  if (idx >= Nn*4) return;
  int n = idx >> 2, h = idx & 3;
  const float* xr = xl + (long)n*128 + h*32;
  float s1 = 0.f, s2 = 0.f;
  #pragma unroll
  for (int k = 0; k < 32; ++k) { float v = xr[k]; s1 += v*attS[h*32+k]; s2 += v*attD[h*32+k]; }
  aS[idx] = s1; aD[idx] = s2;
}

__device__ inline float lrelu(float v){ return v > 0.f ? v : 0.2f*v; }

// GAT: wave per dst node; pass A lane-parallel max; pass B 8-deep pipelined
__global__ __launch_bounds__(256) void k_gat(const unsigned* __restrict__ packed,
    const int* __restrict__ ofs, const int* __restrict__ deg,
    const float* __restrict__ aS, const float* __restrict__ aD,
    const float* __restrict__ xl, const float* __restrict__ gatb,
    float* __restrict__ out, int Nn)
{
  int n = (blockIdx.x*256 + threadIdx.x) >> 6;
  if (n >= Nn) return;
  int lane = threadIdx.x & 63;
  int o = ofs[n], dg = deg[n];

  float4 aD4 = *(const float4*)&aD[(long)n*4];
  float4 aS4 = *(const float4*)&aS[(long)n*4];
  float sl0 = lrelu(aS4.x + aD4.x), sl1 = lrelu(aS4.y + aD4.y);
  float sl2 = lrelu(aS4.z + aD4.z), sl3 = lrelu(aS4.w + aD4.w);

  float m0 = sl0, m1 = sl1, m2 = sl2, m3 = sl3;
  for (int e = lane; e < dg; e += 64) {
    unsigned pk = packed[o + e];
    if (!(pk & SELFBIT)) {
      int s = pk & 0xFFFF;
      float4 a = *(const float4*)&aS[(long)s*4];
      m0 = fmaxf(m0, lrelu(a.x + aD4.x));
      m1 = fmaxf(m1, lrelu(a.y + aD4.y));
      m2 = fmaxf(m2, lrelu(a.z + aD4.z));
      m3 = fmaxf(m3, lrelu(a.w + aD4.w));
    }
  }
  #pragma unroll
  for (int d = 1; d < 64; d <<= 1) {
    m0 = fmaxf(m0, __shfl_xor(m0, d));
    m1 = fmaxf(m1, __shfl_xor(m1, d));
    m2 = fmaxf(m2, __shfl_xor(m2, d));
    m3 = fmaxf(m3, __shfl_xor(m3, d));
  }

  int hh = lane >> 4;
  float mh   = hh == 0 ? m0    : hh == 1 ? m1    : hh == 2 ? m2    : m3;
  float aDnh = hh == 0 ? aD4.x : hh == 1 ? aD4.y : hh == 2 ? aD4.z : aD4.w;
  float slh  = hh == 0 ? sl0   : hh == 1 ? sl1   : hh == 2 ? sl2   : sl3;

  float wself = __expf(slh - mh);
  float den = wself;
  float2 xs = *(const float2*)&xl[(long)n*128 + lane*2];
  float acc0 = xs.x*wself, acc1 = xs.y*wself;

  for (int e0 = 0; e0 < dg; e0 += 8) {
    unsigned pk[8]; float2 v[8]; float as_[8];
    #pragma unroll
    for (int j = 0; j < 8; ++j)
      pk[j] = (e0 + j < dg) ? packed[o + e0 + j] : SELFBIT;
    #pragma unroll
    for (int j = 0; j < 8; ++j) {
      int s = pk[j] & 0xFFFF;
      as_[j] = aS[(long)s*4 + hh];
      v[j]   = *(const float2*)&xl[(long)s*128 + lane*2];
    }
    #pragma unroll
    for (int j = 0; j < 8; ++j) {
      if (!(pk[j] & SELFBIT)) {
        float al = lrelu(as_[j] + aDnh);
        float w = __expf(al - mh);
        den += w;
        acc0 = fmaf(v[j].x, w, acc0);
        acc1 = fmaf(v[j].y, w, acc1);
      }
    }
  }
  float2 r;
  r.x = acc0/den + gatb[lane*2];
  r.y = acc1/den + gatb[lane*2 + 1];
  *(float2*)&out[(long)n*128 + lane*2] = r;
}

extern "C" void kernel_launch(void* const* d_in, const int* in_sizes, int n_in,
                              void* d_out, int out_size, void* d_ws, size_t ws_size,
                              hipStream_t stream) {
  const float* x     = (const float*)d_in[0];
  const int*   eidx  = (const int*)  d_in[1];
  const int*   etype = (const int*)  d_in[2];
  const float* comp  = (const float*)d_in[3];
  const float* basis = (const float*)d_in[4];
  const float* root  = (const float*)d_in[5];
  const float* bias1 = (const float*)d_in[6];
  const float* gatw  = (const float*)d_in[7];
  const float* attS  = (const float*)d_in[8];
  const float* attD  = (const float*)d_in[9];
  const float* gatb  = (const float*)d_in[10];

  int Nn = in_sizes[0] / 128;
  int E  = in_sizes[2];
  const int* src = eidx;
  const int* dst = eidx + E;

  char* ws = (char*)d_ws;
  size_t o = 0;
  float* W    = (float*)(ws + o); o += (size_t)RREL*128*128*4;
  float* h    = (float*)(ws + o); o += (size_t)Nn*128*4;
  float* xl   = (float*)(ws + o); o += (size_t)Nn*128*4;
  float* aS   = (float*)(ws + o); o += (size_t)Nn*4*4;
  float* aD   = (float*)(ws + o); o += (size_t)Nn*4*4;
  int*   deg  = (int*)  (ws + o); o += (size_t)Nn*4;
  int*   ofs  = (int*)  (ws + o); o += (size_t)Nn*4;
  int*   cur  = (int*)  (ws + o); o += (size_t)Nn*4;
  int*   cnt8 = (int*)  (ws + o); o += (size_t)Nn*RREL*4;
  unsigned* packed = (unsigned*)(ws + o); o += (size_t)E*4;

  float* out = (float*)d_out;

  hipMemsetAsync(deg, 0, (size_t)Nn*4, stream);
  hipMemsetAsync(cnt8, 0, (size_t)Nn*RREL*4, stream);

  k_relweights<<<512, 256, 0, stream>>>(comp, basis, W);
  k_hist<<<cdiv(E,256), 256, 0, stream>>>(dst, etype, deg, cnt8, E);
  k_scan<<<1, 1024, 0, stream>>>(deg, ofs, cur, Nn);
  k_permute<<<cdiv(E,256), 256, 0, stream>>>(src, dst, etype, cnt8, cur, packed, E);

  // h = x @ root + bias1
  gemm128<<<cdiv(Nn,32), 256, 0, stream>>>(x, root, h, Nn, 128, bias1, 0);
  // h += sum_r mean_r @ W[r]
  k_rgcn<<<cdiv(Nn,NPB), 256, 0, stream>>>(packed, ofs, deg, x, W, h, Nn);

  // GAT
  gemm128<<<cdiv(Nn,32), 256, 0, stream>>>(h, gatw, xl, Nn, 128, nullptr, 0);
  k_att<<<cdiv((long)Nn*4,256), 256, 0, stream>>>(xl, attS, attD, aS, aD, Nn);
  k_gat<<<cdiv(Nn,4), 256, 0, stream>>>(packed, ofs, deg, aS, aD, xl, gatb, out, Nn);
}

// Round 4
// 347.058 us; speedup vs baseline: 10.8432x; 1.8183x over previous
//
#include <hip/hip_runtime.h>
#include <hip/hip_bf16.h>

#define RREL 8
#define NB 20
#define SELFBIT (1u<<19)
#define KEXT 1152   // 1024 rgcn (8 rel x 128) + 128 root

typedef __attribute__((ext_vector_type(8))) short bf16x8;
typedef __attribute__((ext_vector_type(4))) float f32x4;

static inline int cdiv(long a, long b){ return (int)((a + b - 1)/b); }

__device__ inline float2 b2f2(unsigned u){
  union { unsigned u; __hip_bfloat162 b; } c; c.u = u;
  return __bfloat1622float2(c.b);
}
__device__ inline unsigned f2b2(float x, float y){
  float2 f; f.x = x; f.y = y;
  union { unsigned u; __hip_bfloat162 b; } c; c.b = __float22bfloat162_rn(f);
  return c.u;
}

// B-fragment packing for mfma_f32_16x16x32_bf16:
// lane = ((k>>3)&3)*16 + (o&15), elem = k&7, tile (ks = k>>5, nt = o>>4)
__device__ inline long wpack_idx(int k, int o){
  int ks = k >> 5, nt = o >> 4;
  int lane = (((k >> 3) & 3) << 4) | (o & 15);
  return ((long)((ks*8 + nt)*64 + lane))*8 + (k & 7);
}

// Wb[k][o] for k<1024: basis-combined rel weights; k>=1024: root. Packed, bf16.
__global__ __launch_bounds__(256) void k_relweights(const float* __restrict__ comp,
    const float* __restrict__ basis, const float* __restrict__ root,
    __hip_bfloat16* __restrict__ Wb)
{
  int idx = blockIdx.x*256 + threadIdx.x;   // k*128 + o
  if (idx >= KEXT*128) return;
  int k = idx >> 7, o = idx & 127;
  float s;
  if (k < 1024) {
    int r = k >> 7, io = ((k & 127) << 7) | o;
    s = 0.f;
    #pragma unroll
    for (int b = 0; b < NB; ++b) s += comp[r*NB + b] * basis[b*16384 + io];
  } else {
    s = root[((k - 1024) << 7) | o];
  }
  Wb[wpack_idx(k, o)] = __float2bfloat16(s);
}

__global__ __launch_bounds__(256) void k_packg(const float* __restrict__ gatw,
    __hip_bfloat16* __restrict__ Wg)
{
  int idx = blockIdx.x*256 + threadIdx.x;   // 128*128
  if (idx >= 16384) return;
  int k = idx >> 7, o = idx & 127;
  Wg[wpack_idx(k, o)] = __float2bfloat16(gatw[idx]);
}

// f32 -> bf16, 8 elements per thread
__global__ __launch_bounds__(256) void k_cvt(const float* __restrict__ in,
    __hip_bfloat16* __restrict__ out, int n8)
{
  int i = blockIdx.x*256 + threadIdx.x;
  if (i >= n8) return;
  const float4* ip = (const float4*)in;
  float4 f0 = ip[i*2], f1 = ip[i*2+1];
  uint4 o4;
  o4.x = f2b2(f0.x, f0.y); o4.y = f2b2(f0.z, f0.w);
  o4.z = f2b2(f1.x, f1.y); o4.w = f2b2(f1.z, f1.w);
  ((uint4*)out)[i] = o4;
}

__global__ __launch_bounds__(256) void k_hist(const int* __restrict__ dst,
    const int* __restrict__ et, int* __restrict__ deg, int* __restrict__ cnt8, int E) {
  int e = blockIdx.x*256 + threadIdx.x;
  if (e < E) { int d = dst[e]; atomicAdd(&deg[d], 1); atomicAdd(&cnt8[d*8 + et[e]], 1); }
}

__global__ __launch_bounds__(1024) void k_scan(const int* __restrict__ deg,
    int* __restrict__ ofs, int* __restrict__ cur, int Nn)
{
  __shared__ int wsum[17];
  __shared__ int base_s;
  int t = threadIdx.x, lane = t & 63, wv = t >> 6;
  if (t == 0) base_s = 0;
  __syncthreads();
  for (int c0 = 0; c0 < Nn; c0 += 1024) {
    int i = c0 + t;
    int v = (i < Nn) ? deg[i] : 0;
    int incl = v;
    #pragma unroll
    for (int d = 1; d < 64; d <<= 1) {
      int u = __shfl_up(incl, d);
      if (lane >= d) incl += u;
    }
    if (lane == 63) wsum[wv] = incl;
    __syncthreads();
    if (t == 0) {
      int run = 0;
      #pragma unroll
      for (int k2 = 0; k2 < 16; ++k2) { int s2 = wsum[k2]; wsum[k2] = run; run += s2; }
      wsum[16] = run;
    }
    __syncthreads();
    int base = base_s;
    int excl = base + wsum[wv] + incl - v;
    if (i < Nn) { ofs[i] = excl; cur[i] = excl; }
    __syncthreads();
    if (t == 0) base_s = base + wsum[16];
    __syncthreads();
  }
}

__global__ __launch_bounds__(256) void k_permute(const int* __restrict__ src,
    const int* __restrict__ dst, const int* __restrict__ et,
    const int* __restrict__ cnt8, int* __restrict__ cur,
    unsigned* __restrict__ packed, int E)
{
  int e = blockIdx.x*256 + threadIdx.x;
  if (e >= E) return;
  int d = dst[e], s = src[e], r = et[e];
  int p = atomicAdd(&cur[d], 1);
  unsigned c = (unsigned)cnt8[d*8 + r];
  packed[p] = (unsigned)s | ((unsigned)r << 16) | ((s == d) ? SELFBIT : 0u) | (c << 20);
}

// Fused RGCN: per-node per-rel mean (regs -> swizzled bf16 LDS) + MFMA S@W
#define NPB 16
__global__ __launch_bounds__(256) void k_rgcn(const unsigned* __restrict__ packed,
    const int* __restrict__ ofs, const int* __restrict__ deg,
    const __hip_bfloat16* __restrict__ xb, const __hip_bfloat16* __restrict__ Wb,
    const float* __restrict__ bias1, __hip_bfloat16* __restrict__ hb, int Nn)
{
  __shared__ short S[NPB * KEXT];   // 36 KB, XOR-swizzled rows
  int t = threadIdx.x, lane = t & 63, wv = t >> 6;
  int n0 = blockIdx.x * NPB;
  char* Sbase = (char*)S;

  // phase 1: wave aggregates 4 nodes; 8-deep edge batching; lane owns 2 channels
  for (int ni = 0; ni < 4; ++ni) {
    int nl = wv*4 + ni;
    int n = n0 + nl;
    float a0[RREL] = {}, a1[RREL] = {};
    unsigned selfv = 0;
    if (n < Nn) {
      selfv = *(const unsigned*)&xb[(long)n*128 + lane*2];
      int o = ofs[n], dg = deg[n];
      for (int e0 = 0; e0 < dg; e0 += 8) {
        unsigned pk[8], vv[8];
        #pragma unroll
        for (int j = 0; j < 8; ++j)
          pk[j] = (e0 + j < dg) ? packed[o + e0 + j] : (1u << 20);
        #pragma unroll
        for (int j = 0; j < 8; ++j)
          vv[j] = *(const unsigned*)&xb[(long)(pk[j] & 0xFFFF)*128 + lane*2];
        #pragma unroll
        for (int j = 0; j < 8; ++j) {
          if (e0 + j < dg) {   // wave-uniform
            int r = (pk[j] >> 16) & 7;
            float sc = __builtin_amdgcn_rcpf((float)(pk[j] >> 20));
            float2 v = b2f2(vv[j]);
            float sx = v.x * sc, sy = v.y * sc;
            #pragma unroll
            for (int rr = 0; rr < RREL; ++rr) {
              float mk = (r == rr) ? 1.f : 0.f;
              a0[rr] = fmaf(mk, sx, a0[rr]);
              a1[rr] = fmaf(mk, sy, a1[rr]);
            }
          }
        }
      }
    }
    char* Sr = Sbase + (long)nl*(KEXT*2);
    unsigned swz = (unsigned)((nl & 7) << 4);
    #pragma unroll
    for (int rr = 0; rr < RREL; ++rr)
      *(unsigned*)(Sr + ((rr*256 + lane*4) ^ swz)) = f2b2(a0[rr], a1[rr]);
    *(unsigned*)(Sr + ((2048 + lane*4) ^ swz)) = selfv;   // root slab = x itself
  }
  __syncthreads();

  // phase 2: hb[n0..n0+15][:] = S(16x1152) @ Wb(1152x128) + bias1   (MFMA)
  int col = lane & 15, q = lane >> 4;
  int nt0 = wv*2, nt1 = nt0 + 1;
  const bf16x8* W8 = (const bf16x8*)Wb;
  f32x4 c0 = {0.f,0.f,0.f,0.f}, c1 = {0.f,0.f,0.f,0.f};
  unsigned rswz = (unsigned)((col & 7) << 4);
  for (int ks = 0; ks < KEXT/32; ++ks) {
    bf16x8 a = *(const bf16x8*)(Sbase + (long)col*(KEXT*2)
                                + (((unsigned)(ks*64 + q*16)) ^ rswz));
    bf16x8 b0 = W8[(ks*8 + nt0)*64 + lane];
    bf16x8 b1 = W8[(ks*8 + nt1)*64 + lane];
    c0 = __builtin_amdgcn_mfma_f32_16x16x32_bf16(a, b0, c0, 0, 0, 0);
    c1 = __builtin_amdgcn_mfma_f32_16x16x32_bf16(a, b1, c1, 0, 0, 0);
  }
  #pragma unroll
  for (int r = 0; r < 4; ++r) {
    int row = n0 + q*4 + r;
    if (row < Nn) {
      hb[(long)row*128 + nt0*16 + col] = __float2bfloat16(c0[r] + bias1[nt0*16 + col]);
      hb[(long)row*128 + nt1*16 + col] = __float2bfloat16(c1[r] + bias1[nt1*16 + col]);
    }
  }
}

// xlb = hb @ gatw  (MFMA, A-fragments straight from global hb)
__global__ __launch_bounds__(256) void k_xl(const __hip_bfloat16* __restrict__ hb,
    const __hip_bfloat16* __restrict__ Wg, __hip_bfloat16* __restrict__ xlb, int Nn)
{
  int t = threadIdx.x, lane = t & 63, wv = t >> 6;
  int n0 = blockIdx.x * 16;
  int col = lane & 15, q = lane >> 4;
  int nt0 = wv*2, nt1 = nt0 + 1;
  int arow = n0 + col; if (arow >= Nn) arow = Nn - 1;
  const bf16x8* W8 = (const bf16x8*)Wg;
  f32x4 c0 = {0.f,0.f,0.f,0.f}, c1 = {0.f,0.f,0.f,0.f};
  #pragma unroll
  for (int ks = 0; ks < 4; ++ks) {
    bf16x8 a = *(const bf16x8*)&hb[(long)arow*128 + ks*32 + q*8];
    bf16x8 b0 = W8[(ks*8 + nt0)*64 + lane];
    bf16x8 b1 = W8[(ks*8 + nt1)*64 + lane];
    c0 = __builtin_amdgcn_mfma_f32_16x16x32_bf16(a, b0, c0, 0, 0, 0);
    c1 = __builtin_amdgcn_mfma_f32_16x16x32_bf16(a, b1, c1, 0, 0, 0);
  }
  #pragma unroll
  for (int r = 0; r < 4; ++r) {
    int row = n0 + q*4 + r;
    if (row < Nn) {
      xlb[(long)row*128 + nt0*16 + col] = __float2bfloat16(c0[r]);
      xlb[(long)row*128 + nt1*16 + col] = __float2bfloat16(c1[r]);
    }
  }
}

__global__ __launch_bounds__(256) void k_att(const __hip_bfloat16* __restrict__ xlb,
    const float* __restrict__ attS, const float* __restrict__ attD,
    float* __restrict__ aS, float* __restrict__ aD, int Nn)
{
  int idx = blockIdx.x*256 + threadIdx.x;
  if (idx >= Nn*4) return;
  int n = idx >> 2, hh = idx & 3;
  const __hip_bfloat16* xr = xlb + (long)n*128 + hh*32;
  float s1 = 0.f, s2 = 0.f;
  #pragma unroll
  for (int k = 0; k < 32; k += 2) {
    float2 v = b2f2(*(const unsigned*)&xr[k]);
    s1 += v.x*attS[hh*32+k] + v.y*attS[hh*32+k+1];
    s2 += v.x*attD[hh*32+k] + v.y*attD[hh*32+k+1];
  }
  aS[idx] = s1; aD[idx] = s2;
}

__device__ inline float lrelu(float v){ return v > 0.f ? v : 0.2f*v; }

__global__ __launch_bounds__(256) void k_gat(const unsigned* __restrict__ packed,
    const int* __restrict__ ofs, const int* __restrict__ deg,
    const float* __restrict__ aS, const float* __restrict__ aD,
    const __hip_bfloat16* __restrict__ xlb, const float* __restrict__ gatb,
    float* __restrict__ out, int Nn)
{
  int n = (blockIdx.x*256 + threadIdx.x) >> 6;
  if (n >= Nn) return;
  int lane = threadIdx.x & 63;
  int o = ofs[n], dg = deg[n];

  float4 aD4 = *(const float4*)&aD[(long)n*4];
  float4 aS4 = *(const float4*)&aS[(long)n*4];
  float sl0 = lrelu(aS4.x + aD4.x), sl1 = lrelu(aS4.y + aD4.y);
  float sl2 = lrelu(aS4.z + aD4.z), sl3 = lrelu(aS4.w + aD4.w);

  float m0 = sl0, m1 = sl1, m2 = sl2, m3 = sl3;
  for (int e = lane; e < dg; e += 64) {
    unsigned pk = packed[o + e];
    if (!(pk & SELFBIT)) {
      int s = pk & 0xFFFF;
      float4 a = *(const float4*)&aS[(long)s*4];
      m0 = fmaxf(m0, lrelu(a.x + aD4.x));
      m1 = fmaxf(m1, lrelu(a.y + aD4.y));
      m2 = fmaxf(m2, lrelu(a.z + aD4.z));
      m3 = fmaxf(m3, lrelu(a.w + aD4.w));
    }
  }
  #pragma unroll
  for (int d = 1; d < 64; d <<= 1) {
    m0 = fmaxf(m0, __shfl_xor(m0, d));
    m1 = fmaxf(m1, __shfl_xor(m1, d));
    m2 = fmaxf(m2, __shfl_xor(m2, d));
    m3 = fmaxf(m3, __shfl_xor(m3, d));
  }

  int hh = lane >> 4;
  float mh   = hh == 0 ? m0    : hh == 1 ? m1    : hh == 2 ? m2    : m3;
  float aDnh = hh == 0 ? aD4.x : hh == 1 ? aD4.y : hh == 2 ? aD4.z : aD4.w;
  float slh  = hh == 0 ? sl0   : hh == 1 ? sl1   : hh == 2 ? sl2   : sl3;

  float wself = __expf(slh - mh);
  float den = wself;
  float2 xs = b2f2(*(const unsigned*)&xlb[(long)n*128 + lane*2]);
  float acc0 = xs.x*wself, acc1 = xs.y*wself;

  for (int e0 = 0; e0 < dg; e0 += 8) {
    unsigned pk[8], vv[8]; float as_[8];
    #pragma unroll
    for (int j = 0; j < 8; ++j)
      pk[j] = (e0 + j < dg) ? packed[o + e0 + j] : SELFBIT;
    #pragma unroll
    for (int j = 0; j < 8; ++j) {
      int s = pk[j] & 0xFFFF;
      as_[j] = aS[(long)s*4 + hh];
      vv[j]  = *(const unsigned*)&xlb[(long)s*128 + lane*2];
    }
    #pragma unroll
    for (int j = 0; j < 8; ++j) {
      if (!(pk[j] & SELFBIT)) {
        float al = lrelu(as_[j] + aDnh);
        float w = __expf(al - mh);
        den += w;
        float2 v = b2f2(vv[j]);
        acc0 = fmaf(v.x, w, acc0);
        acc1 = fmaf(v.y, w, acc1);
      }
    }
  }
  float2 r;
  r.x = acc0/den + gatb[lane*2];
  r.y = acc1/den + gatb[lane*2 + 1];
  *(float2*)&out[(long)n*128 + lane*2] = r;
}

extern "C" void kernel_launch(void* const* d_in, const int* in_sizes, int n_in,
                              void* d_out, int out_size, void* d_ws, size_t ws_size,
                              hipStream_t stream) {
  const float* x     = (const float*)d_in[0];
  const int*   eidx  = (const int*)  d_in[1];
  const int*   etype = (const int*)  d_in[2];
  const float* comp  = (const float*)d_in[3];
  const float* basis = (const float*)d_in[4];
  const float* root  = (const float*)d_in[5];
  const float* bias1 = (const float*)d_in[6];
  const float* gatw  = (const float*)d_in[7];
  const float* attS  = (const float*)d_in[8];
  const float* attD  = (const float*)d_in[9];
  const float* gatb  = (const float*)d_in[10];

  int Nn = in_sizes[0] / 128;
  int E  = in_sizes[2];
  const int* src = eidx;
  const int* dst = eidx + E;

  char* ws = (char*)d_ws;
  size_t o = 0;
  __hip_bfloat16* Wb  = (__hip_bfloat16*)(ws + o); o += (size_t)KEXT*128*2;
  __hip_bfloat16* Wg  = (__hip_bfloat16*)(ws + o); o += (size_t)128*128*2;
  __hip_bfloat16* xb  = (__hip_bfloat16*)(ws + o); o += (size_t)Nn*128*2;
  __hip_bfloat16* hb  = (__hip_bfloat16*)(ws + o); o += (size_t)Nn*128*2;
  __hip_bfloat16* xlb = (__hip_bfloat16*)(ws + o); o += (size_t)Nn*128*2;
  float* aS   = (float*)(ws + o); o += (size_t)Nn*4*4;
  float* aD   = (float*)(ws + o); o += (size_t)Nn*4*4;
  int*   deg  = (int*)  (ws + o); o += (size_t)Nn*4;
  int*   ofs  = (int*)  (ws + o); o += (size_t)Nn*4;
  int*   cur  = (int*)  (ws + o); o += (size_t)Nn*4;
  int*   cnt8 = (int*)  (ws + o); o += (size_t)Nn*RREL*4;
  unsigned* packed = (unsigned*)(ws + o); o += (size_t)E*4;

  float* out = (float*)d_out;

  hipMemsetAsync(deg, 0, (size_t)Nn*4, stream);
  hipMemsetAsync(cnt8, 0, (size_t)Nn*RREL*4, stream);

  k_relweights<<<cdiv(KEXT*128,256), 256, 0, stream>>>(comp, basis, root, Wb);
  k_packg<<<64, 256, 0, stream>>>(gatw, Wg);
  k_cvt<<<cdiv((long)Nn*16,256), 256, 0, stream>>>(x, xb, Nn*16);
  k_hist<<<cdiv(E,256), 256, 0, stream>>>(dst, etype, deg, cnt8, E);
  k_scan<<<1, 1024, 0, stream>>>(deg, ofs, cur, Nn);
  k_permute<<<cdiv(E,256), 256, 0, stream>>>(src, dst, etype, cnt8, cur, packed, E);

  k_rgcn<<<cdiv(Nn,NPB), 256, 0, stream>>>(packed, ofs, deg, xb, Wb, bias1, hb, Nn);
  k_xl<<<cdiv(Nn,16), 256, 0, stream>>>(hb, Wg, xlb, Nn);
  k_att<<<cdiv((long)Nn*4,256), 256, 0, stream>>>(xlb, attS, attD, aS, aD, Nn);
  k_gat<<<cdiv(Nn,4), 256, 0, stream>>>(packed, ofs, deg, aS, aD, xlb, gatb, out, Nn);
}

// Round 5
// 328.442 us; speedup vs baseline: 11.4578x; 1.0567x over previous
//
#include <hip/hip_runtime.h>
#include <hip/hip_bf16.h>

#define RREL 8
#define NB 20
#define SELFBIT (1u<<19)
#define KEXT 1152   // 1024 rgcn (8 rel x 128) + 128 root

typedef __attribute__((ext_vector_type(8))) short bf16x8;
typedef __attribute__((ext_vector_type(4))) float f32x4;

static inline int cdiv(long a, long b){ return (int)((a + b - 1)/b); }

__device__ inline float2 b2f2(unsigned u){
  union { unsigned u; __hip_bfloat162 b; } c; c.u = u;
  return __bfloat1622float2(c.b);
}
__device__ inline unsigned f2b2(float x, float y){
  float2 f; f.x = x; f.y = y;
  union { unsigned u; __hip_bfloat162 b; } c; c.b = __float22bfloat162_rn(f);
  return c.u;
}

// B-fragment packing for mfma_f32_16x16x32_bf16:
// lane = ((k>>3)&3)*16 + (o&15), elem = k&7, tile (ks = k>>5, nt = o>>4)
__device__ inline long wpack_idx(int k, int o){
  int ks = k >> 5, nt = o >> 4;
  int lane = (((k >> 3) & 3) << 4) | (o & 15);
  return ((long)((ks*8 + nt)*64 + lane))*8 + (k & 7);
}

__global__ __launch_bounds__(256) void k_relweights(const float* __restrict__ comp,
    const float* __restrict__ basis, const float* __restrict__ root,
    __hip_bfloat16* __restrict__ Wb)
{
  int idx = blockIdx.x*256 + threadIdx.x;   // k*128 + o
  if (idx >= KEXT*128) return;
  int k = idx >> 7, o = idx & 127;
  float s;
  if (k < 1024) {
    int r = k >> 7, io = ((k & 127) << 7) | o;
    s = 0.f;
    #pragma unroll
    for (int b = 0; b < NB; ++b) s += comp[r*NB + b] * basis[b*16384 + io];
  } else {
    s = root[((k - 1024) << 7) | o];
  }
  Wb[wpack_idx(k, o)] = __float2bfloat16(s);
}

__global__ __launch_bounds__(256) void k_packg(const float* __restrict__ gatw,
    __hip_bfloat16* __restrict__ Wg)
{
  int idx = blockIdx.x*256 + threadIdx.x;   // 128*128
  if (idx >= 16384) return;
  int k = idx >> 7, o = idx & 127;
  Wg[wpack_idx(k, o)] = __float2bfloat16(gatw[idx]);
}

__global__ __launch_bounds__(256) void k_cvt(const float* __restrict__ in,
    __hip_bfloat16* __restrict__ out, int n8)
{
  int i = blockIdx.x*256 + threadIdx.x;
  if (i >= n8) return;
  const float4* ip = (const float4*)in;
  float4 f0 = ip[i*2], f1 = ip[i*2+1];
  uint4 o4;
  o4.x = f2b2(f0.x, f0.y); o4.y = f2b2(f0.z, f0.w);
  o4.z = f2b2(f1.x, f1.y); o4.w = f2b2(f1.z, f1.w);
  ((uint4*)out)[i] = o4;
}

__global__ __launch_bounds__(256) void k_hist(const int* __restrict__ dst,
    const int* __restrict__ et, int* __restrict__ deg, int* __restrict__ cnt8, int E) {
  int e = blockIdx.x*256 + threadIdx.x;
  if (e < E) { int d = dst[e]; atomicAdd(&deg[d], 1); atomicAdd(&cnt8[d*8 + et[e]], 1); }
}

__global__ __launch_bounds__(1024) void k_scan(const int* __restrict__ deg,
    int* __restrict__ ofs, int Nn)
{
  __shared__ int wsum[17];
  __shared__ int base_s;
  int t = threadIdx.x, lane = t & 63, wv = t >> 6;
  if (t == 0) base_s = 0;
  __syncthreads();
  for (int c0 = 0; c0 < Nn; c0 += 1024) {
    int i = c0 + t;
    int v = (i < Nn) ? deg[i] : 0;
    int incl = v;
    #pragma unroll
    for (int d = 1; d < 64; d <<= 1) {
      int u = __shfl_up(incl, d);
      if (lane >= d) incl += u;
    }
    if (lane == 63) wsum[wv] = incl;
    __syncthreads();
    if (t == 0) {
      int run = 0;
      #pragma unroll
      for (int k2 = 0; k2 < 16; ++k2) { int s2 = wsum[k2]; wsum[k2] = run; run += s2; }
      wsum[16] = run;
    }
    __syncthreads();
    int base = base_s;
    int excl = base + wsum[wv] + incl - v;
    if (i < Nn) ofs[i] = excl;
    __syncthreads();
    if (t == 0) base_s = base + wsum[16];
    __syncthreads();
  }
}

// per-(node,rel) offsets within the node's CSR segment
__global__ __launch_bounds__(256) void k_ofs8(const int* __restrict__ ofs,
    const int* __restrict__ cnt8, int* __restrict__ cur8, int Nn)
{
  int n = blockIdx.x*256 + threadIdx.x;
  if (n >= Nn) return;
  int run = ofs[n];
  #pragma unroll
  for (int r = 0; r < 8; ++r) { int c = cnt8[n*8 + r]; cur8[n*8 + r] = run; run += c; }
}

__global__ __launch_bounds__(256) void k_permute(const int* __restrict__ src,
    const int* __restrict__ dst, const int* __restrict__ et,
    const int* __restrict__ cnt8, int* __restrict__ cur8,
    unsigned* __restrict__ packed, int E)
{
  int e = blockIdx.x*256 + threadIdx.x;
  if (e >= E) return;
  int d = dst[e], s = src[e], r = et[e];
  int p = atomicAdd(&cur8[d*8 + r], 1);
  unsigned c = (unsigned)cnt8[d*8 + r];
  packed[p] = (unsigned)s | ((unsigned)r << 16) | ((s == d) ? SELFBIT : 0u) | (c << 20);
}

// Fused RGCN: rel-sorted aggregation (flush-on-boundary) + MFMA S@W
#define NPB 16
__global__ __launch_bounds__(256) void k_rgcn(const unsigned* __restrict__ packed,
    const int* __restrict__ ofs, const int* __restrict__ deg,
    const __hip_bfloat16* __restrict__ xb, const __hip_bfloat16* __restrict__ Wb,
    const float* __restrict__ bias1, __hip_bfloat16* __restrict__ hb, int Nn)
{
  __shared__ short S[NPB * KEXT];   // 36 KB, XOR-swizzled rows
  int t = threadIdx.x, lane = t & 63, wv = t >> 6;
  int n0 = blockIdx.x * NPB;
  char* Sbase = (char*)S;

  // zero S
  for (int i = t; i < NPB*KEXT/8; i += 256) ((uint4*)S)[i] = make_uint4(0,0,0,0);
  __syncthreads();

  // phase 1: wave aggregates 4 nodes; edges sorted by rel; flush on boundary
  for (int ni = 0; ni < 4; ++ni) {
    int nl = wv*4 + ni;
    int n = n0 + nl;
    if (n >= Nn) continue;
    char* Sr = Sbase + (long)nl*(KEXT*2);
    unsigned swz = (unsigned)((nl & 7) << 4);
    *(unsigned*)(Sr + ((2048 + lane*4) ^ swz)) =
        *(const unsigned*)&xb[(long)n*128 + lane*2];   // root slab = x row
    int o = ofs[n], dg = deg[n];
    if (dg == 0) continue;
    float a0 = 0.f, a1 = 0.f;
    int pr = -1; unsigned lastpk = 1u << 20;
    for (int e0 = 0; e0 < dg; e0 += 8) {
      unsigned pk[8], vv[8];
      #pragma unroll
      for (int j = 0; j < 8; ++j) {
        int idx = e0 + j; idx = (idx < dg) ? idx : (dg - 1);
        pk[j] = packed[o + idx];
      }
      #pragma unroll
      for (int j = 0; j < 8; ++j)
        vv[j] = *(const unsigned*)&xb[(long)(pk[j] & 0xFFFF)*128 + lane*2];
      #pragma unroll
      for (int j = 0; j < 8; ++j) {
        if (e0 + j < dg) {     // wave-uniform
          int r = (pk[j] >> 16) & 7;
          if (r != pr) {       // wave-uniform (sorted by rel)
            if (pr >= 0) {
              float sc = __builtin_amdgcn_rcpf((float)(lastpk >> 20));
              *(unsigned*)(Sr + ((pr*256 + lane*4) ^ swz)) = f2b2(a0*sc, a1*sc);
            }
            a0 = 0.f; a1 = 0.f; pr = r;
          }
          lastpk = pk[j];
          float2 v = b2f2(vv[j]);
          a0 += v.x; a1 += v.y;
        }
      }
    }
    float sc = __builtin_amdgcn_rcpf((float)(lastpk >> 20));
    *(unsigned*)(Sr + ((pr*256 + lane*4) ^ swz)) = f2b2(a0*sc, a1*sc);
  }
  __syncthreads();

  // phase 2: hb[n0..n0+15][:] = S(16x1152) @ Wb(1152x128) + bias1   (MFMA)
  int col = lane & 15, q = lane >> 4;
  int nt0 = wv*2, nt1 = nt0 + 1;
  const bf16x8* W8 = (const bf16x8*)Wb;
  f32x4 c0 = {0.f,0.f,0.f,0.f}, c1 = {0.f,0.f,0.f,0.f};
  unsigned rswz = (unsigned)((col & 7) << 4);
  for (int ks = 0; ks < KEXT/32; ++ks) {
    bf16x8 a = *(const bf16x8*)(Sbase + (long)col*(KEXT*2)
                                + (((unsigned)(ks*64 + q*16)) ^ rswz));
    bf16x8 b0 = W8[(ks*8 + nt0)*64 + lane];
    bf16x8 b1 = W8[(ks*8 + nt1)*64 + lane];
    c0 = __builtin_amdgcn_mfma_f32_16x16x32_bf16(a, b0, c0, 0, 0, 0);
    c1 = __builtin_amdgcn_mfma_f32_16x16x32_bf16(a, b1, c1, 0, 0, 0);
  }
  #pragma unroll
  for (int r = 0; r < 4; ++r) {
    int row = n0 + q*4 + r;
    if (row < Nn) {
      hb[(long)row*128 + nt0*16 + col] = __float2bfloat16(c0[r] + bias1[nt0*16 + col]);
      hb[(long)row*128 + nt1*16 + col] = __float2bfloat16(c1[r] + bias1[nt1*16 + col]);
    }
  }
}

// xlb = hb @ gatw  (MFMA)
__global__ __launch_bounds__(256) void k_xl(const __hip_bfloat16* __restrict__ hb,
    const __hip_bfloat16* __restrict__ Wg, __hip_bfloat16* __restrict__ xlb, int Nn)
{
  int t = threadIdx.x, lane = t & 63, wv = t >> 6;
  int n0 = blockIdx.x * 16;
  int col = lane & 15, q = lane >> 4;
  int nt0 = wv*2, nt1 = nt0 + 1;
  int arow = n0 + col; if (arow >= Nn) arow = Nn - 1;
  const bf16x8* W8 = (const bf16x8*)Wg;
  f32x4 c0 = {0.f,0.f,0.f,0.f}, c1 = {0.f,0.f,0.f,0.f};
  #pragma unroll
  for (int ks = 0; ks < 4; ++ks) {
    bf16x8 a = *(const bf16x8*)&hb[(long)arow*128 + ks*32 + q*8];
    bf16x8 b0 = W8[(ks*8 + nt0)*64 + lane];
    bf16x8 b1 = W8[(ks*8 + nt1)*64 + lane];
    c0 = __builtin_amdgcn_mfma_f32_16x16x32_bf16(a, b0, c0, 0, 0, 0);
    c1 = __builtin_amdgcn_mfma_f32_16x16x32_bf16(a, b1, c1, 0, 0, 0);
  }
  #pragma unroll
  for (int r = 0; r < 4; ++r) {
    int row = n0 + q*4 + r;
    if (row < Nn) {
      xlb[(long)row*128 + nt0*16 + col] = __float2bfloat16(c0[r]);
      xlb[(long)row*128 + nt1*16 + col] = __float2bfloat16(c1[r]);
    }
  }
}

__global__ __launch_bounds__(256) void k_att(const __hip_bfloat16* __restrict__ xlb,
    const float* __restrict__ attS, const float* __restrict__ attD,
    float* __restrict__ aS, float* __restrict__ aD, int Nn)
{
  int idx = blockIdx.x*256 + threadIdx.x;
  if (idx >= Nn*4) return;
  int n = idx >> 2, hh = idx & 3;
  const __hip_bfloat16* xr = xlb + (long)n*128 + hh*32;
  float s1 = 0.f, s2 = 0.f;
  #pragma unroll
  for (int k = 0; k < 32; k += 2) {
    float2 v = b2f2(*(const unsigned*)&xr[k]);
    s1 += v.x*attS[hh*32+k] + v.y*attS[hh*32+k+1];
    s2 += v.x*attD[hh*32+k] + v.y*attD[hh*32+k+1];
  }
  aS[idx] = s1; aD[idx] = s2;
}

__device__ inline float lrelu(float v){ return v > 0.f ? v : 0.2f*v; }

// GAT: wave per dst node; single pass, no-max softmax (logits bounded)
__global__ __launch_bounds__(256) void k_gat(const unsigned* __restrict__ packed,
    const int* __restrict__ ofs, const int* __restrict__ deg,
    const float* __restrict__ aS, const float* __restrict__ aD,
    const __hip_bfloat16* __restrict__ xlb, const float* __restrict__ gatb,
    float* __restrict__ out, int Nn)
{
  int n = (blockIdx.x*256 + threadIdx.x) >> 6;
  if (n >= Nn) return;
  int lane = threadIdx.x & 63;
  int o = ofs[n], dg = deg[n];
  int hh = lane >> 4;

  float4 aD4 = *(const float4*)&aD[(long)n*4];
  float4 aS4 = *(const float4*)&aS[(long)n*4];
  float aDnh = hh == 0 ? aD4.x : hh == 1 ? aD4.y : hh == 2 ? aD4.z : aD4.w;
  float aSnh = hh == 0 ? aS4.x : hh == 1 ? aS4.y : hh == 2 ? aS4.z : aS4.w;

  float wself = __expf(lrelu(aSnh + aDnh));
  float den = wself;
  float2 xs = b2f2(*(const unsigned*)&xlb[(long)n*128 + lane*2]);
  float acc0 = xs.x*wself, acc1 = xs.y*wself;

  for (int e0 = 0; e0 < dg; e0 += 8) {
    unsigned pk[8], vv[8]; float as_[8];
    #pragma unroll
    for (int j = 0; j < 8; ++j) {
      int idx = e0 + j; idx = (idx < dg) ? idx : (dg - 1);
      pk[j] = packed[o + idx];
    }
    #pragma unroll
    for (int j = 0; j < 8; ++j) {
      int s = pk[j] & 0xFFFF;
      as_[j] = aS[(long)s*4 + hh];
      vv[j]  = *(const unsigned*)&xlb[(long)s*128 + lane*2];
    }
    #pragma unroll
    for (int j = 0; j < 8; ++j) {
      bool ok = (e0 + j < dg) && !(pk[j] & SELFBIT);
      float w = __expf(lrelu(as_[j] + aDnh));
      w = ok ? w : 0.f;
      den += w;
      float2 v = b2f2(vv[j]);
      acc0 = fmaf(v.x, w, acc0);
      acc1 = fmaf(v.y, w, acc1);
    }
  }
  float2 r;
  float rd = 1.f / den;
  r.x = acc0*rd + gatb[lane*2];
  r.y = acc1*rd + gatb[lane*2 + 1];
  *(float2*)&out[(long)n*128 + lane*2] = r;
}

extern "C" void kernel_launch(void* const* d_in, const int* in_sizes, int n_in,
                              void* d_out, int out_size, void* d_ws, size_t ws_size,
                              hipStream_t stream) {
  const float* x     = (const float*)d_in[0];
  const int*   eidx  = (const int*)  d_in[1];
  const int*   etype = (const int*)  d_in[2];
  const float* comp  = (const float*)d_in[3];
  const float* basis = (const float*)d_in[4];
  const float* root  = (const float*)d_in[5];
  const float* bias1 = (const float*)d_in[6];
  const float* gatw  = (const float*)d_in[7];
  const float* attS  = (const float*)d_in[8];
  const float* attD  = (const float*)d_in[9];
  const float* gatb  = (const float*)d_in[10];

  int Nn = in_sizes[0] / 128;
  int E  = in_sizes[2];
  const int* src = eidx;
  const int* dst = eidx + E;

  char* ws = (char*)d_ws;
  size_t o = 0;
  __hip_bfloat16* Wb  = (__hip_bfloat16*)(ws + o); o += (size_t)KEXT*128*2;
  __hip_bfloat16* Wg  = (__hip_bfloat16*)(ws + o); o += (size_t)128*128*2;
  __hip_bfloat16* xb  = (__hip_bfloat16*)(ws + o); o += (size_t)Nn*128*2;
  __hip_bfloat16* hb  = (__hip_bfloat16*)(ws + o); o += (size_t)Nn*128*2;
  __hip_bfloat16* xlb = (__hip_bfloat16*)(ws + o); o += (size_t)Nn*128*2;
  float* aS   = (float*)(ws + o); o += (size_t)Nn*4*4;
  float* aD   = (float*)(ws + o); o += (size_t)Nn*4*4;
  int*   deg  = (int*)  (ws + o); o += (size_t)Nn*4;
  int*   ofs  = (int*)  (ws + o); o += (size_t)Nn*4;
  int*   cnt8 = (int*)  (ws + o); o += (size_t)Nn*RREL*4;
  int*   cur8 = (int*)  (ws + o); o += (size_t)Nn*RREL*4;
  unsigned* packed = (unsigned*)(ws + o); o += (size_t)E*4;

  float* out = (float*)d_out;

  hipMemsetAsync(deg, 0, (size_t)Nn*4, stream);
  hipMemsetAsync(cnt8, 0, (size_t)Nn*RREL*4, stream);

  k_relweights<<<cdiv(KEXT*128,256), 256, 0, stream>>>(comp, basis, root, Wb);
  k_packg<<<64, 256, 0, stream>>>(gatw, Wg);
  k_cvt<<<cdiv((long)Nn*16,256), 256, 0, stream>>>(x, xb, Nn*16);
  k_hist<<<cdiv(E,256), 256, 0, stream>>>(dst, etype, deg, cnt8, E);
  k_scan<<<1, 1024, 0, stream>>>(deg, ofs, Nn);
  k_ofs8<<<cdiv(Nn,256), 256, 0, stream>>>(ofs, cnt8, cur8, Nn);
  k_permute<<<cdiv(E,256), 256, 0, stream>>>(src, dst, etype, cnt8, cur8, packed, E);

  k_rgcn<<<cdiv(Nn,NPB), 256, 0, stream>>>(packed, ofs, deg, xb, Wb, bias1, hb, Nn);
  k_xl<<<cdiv(Nn,16), 256, 0, stream>>>(hb, Wg, xlb, Nn);
  k_att<<<cdiv((long)Nn*4,256), 256, 0, stream>>>(xlb, attS, attD, aS, aD, Nn);
  k_gat<<<cdiv(Nn,4), 256, 0, stream>>>(packed, ofs, deg, aS, aD, xlb, gatb, out, Nn);
}

// Round 6
// 272.731 us; speedup vs baseline: 13.7982x; 1.2043x over previous
//
#include <hip/hip_runtime.h>
#include <hip/hip_bf16.h>

#define RREL 8
#define NB 20
#define SELFBIT (1u<<19)
#define KEXT 1152   // 1024 rgcn (8 rel x 128) + 128 root

typedef __attribute__((ext_vector_type(8))) short bf16x8;
typedef __attribute__((ext_vector_type(4))) float f32x4;

static inline int cdiv(long a, long b){ return (int)((a + b - 1)/b); }

__device__ inline float2 b2f2(unsigned u){
  union { unsigned u; __hip_bfloat162 b; } c; c.u = u;
  return __bfloat1622float2(c.b);
}
__device__ inline unsigned f2b2(float x, float y){
  float2 f; f.x = x; f.y = y;
  union { unsigned u; __hip_bfloat162 b; } c; c.b = __float22bfloat162_rn(f);
  return c.u;
}

// B-fragment packing for mfma_f32_16x16x32_bf16:
// lane = ((k>>3)&3)*16 + (o&15), elem = k&7, tile (ks = k>>5, nt = o>>4)
__device__ inline long wpack_idx(int k, int o){
  int ks = k >> 5, nt = o >> 4;
  int lane = (((k >> 3) & 3) << 4) | (o & 15);
  return ((long)((ks*8 + nt)*64 + lane))*8 + (k & 7);
}

// merged prep: rel-weights pack + gatw pack + x->bf16 cvt
__global__ __launch_bounds__(256) void k_prep(const float* __restrict__ comp,
    const float* __restrict__ basis, const float* __restrict__ root,
    const float* __restrict__ gatw, const float* __restrict__ x,
    __hip_bfloat16* __restrict__ Wb, __hip_bfloat16* __restrict__ Wg,
    __hip_bfloat16* __restrict__ xb, int Nn)
{
  int bid = blockIdx.x, t = threadIdx.x;
  if (bid < 576) {                      // Wb: KEXT*128 elems
    int idx = bid*256 + t;
    int k = idx >> 7, o = idx & 127;
    float s;
    if (k < 1024) {
      int r = k >> 7, io = ((k & 127) << 7) | o;
      s = 0.f;
      #pragma unroll
      for (int b = 0; b < NB; ++b) s += comp[r*NB + b] * basis[b*16384 + io];
    } else {
      s = root[((k - 1024) << 7) | o];
    }
    Wb[wpack_idx(k, o)] = __float2bfloat16(s);
  } else if (bid < 640) {               // Wg: 128*128
    int idx = (bid - 576)*256 + t;
    int k = idx >> 7, o = idx & 127;
    Wg[wpack_idx(k, o)] = __float2bfloat16(gatw[idx]);
  } else {                              // cvt: Nn*16 groups of 8 floats
    int i = (bid - 640)*256 + t;
    if (i >= Nn*16) return;
    const float4* ip = (const float4*)x;
    float4 f0 = ip[i*2], f1 = ip[i*2+1];
    uint4 o4;
    o4.x = f2b2(f0.x, f0.y); o4.y = f2b2(f0.z, f0.w);
    o4.z = f2b2(f1.x, f1.y); o4.w = f2b2(f1.z, f1.w);
    ((uint4*)xb)[i] = o4;
  }
}

__global__ __launch_bounds__(256) void k_hist(const int* __restrict__ dst,
    const int* __restrict__ et, int* __restrict__ deg, int* __restrict__ cnt8, int E) {
  int e = blockIdx.x*256 + threadIdx.x;
  if (e < E) { int d = dst[e]; atomicAdd(&deg[d], 1); atomicAdd(&cnt8[d*8 + et[e]], 1); }
}

// scan phase A: per-block (1024 nodes) degree sums
__global__ __launch_bounds__(256) void k_scanA(const int* __restrict__ deg,
    int* __restrict__ bsum, int Nn)
{
  __shared__ int wsum[4];
  int b = blockIdx.x, t = threadIdx.x, lane = t & 63, wv = t >> 6;
  int base = b*1024 + t*4;
  int s = 0;
  #pragma unroll
  for (int j = 0; j < 4; ++j) { int i = base + j; if (i < Nn) s += deg[i]; }
  #pragma unroll
  for (int d = 1; d < 64; d <<= 1) s += __shfl_xor(s, d);
  if (lane == 0) wsum[wv] = s;
  __syncthreads();
  if (t == 0) bsum[b] = wsum[0] + wsum[1] + wsum[2] + wsum[3];
}

// scan phase B: exclusive scan of bsum (1 wave)
__global__ __launch_bounds__(64) void k_scanB(int* __restrict__ bsum, int B)
{
  int lane = threadIdx.x & 63;
  int carry = 0;
  for (int c0 = 0; c0 < B; c0 += 64) {
    int i = c0 + lane;
    int v = (i < B) ? bsum[i] : 0;
    int incl = v;
    #pragma unroll
    for (int d = 1; d < 64; d <<= 1) {
      int u = __shfl_up(incl, d);
      if (lane >= d) incl += u;
    }
    int tot = __shfl(incl, 63);
    if (i < B) bsum[i] = carry + incl - v;
    carry += tot;
  }
}

// scan phase C: per-node ofs + per-(node,rel) cur8
__global__ __launch_bounds__(256) void k_scanC(const int* __restrict__ deg,
    const int* __restrict__ bsum, const int* __restrict__ cnt8,
    int* __restrict__ ofs, int* __restrict__ cur8, int Nn)
{
  __shared__ int wsum[5];
  int b = blockIdx.x, t = threadIdx.x, lane = t & 63, wv = t >> 6;
  int base = b*1024 + t*4;
  int dv[4]; int ts = 0;
  #pragma unroll
  for (int j = 0; j < 4; ++j) { int i = base + j; dv[j] = (i < Nn) ? deg[i] : 0; ts += dv[j]; }
  int incl = ts;
  #pragma unroll
  for (int d = 1; d < 64; d <<= 1) {
    int u = __shfl_up(incl, d);
    if (lane >= d) incl += u;
  }
  if (lane == 63) wsum[wv] = incl;
  __syncthreads();
  if (t == 0) {
    int run = 0;
    #pragma unroll
    for (int k = 0; k < 4; ++k) { int s2 = wsum[k]; wsum[k] = run; run += s2; }
  }
  __syncthreads();
  int run = bsum[b] + wsum[wv] + incl - ts;
  #pragma unroll
  for (int j = 0; j < 4; ++j) {
    int i = base + j;
    if (i < Nn) {
      ofs[i] = run;
      int rr = run;
      #pragma unroll
      for (int r = 0; r < 8; ++r) { cur8[i*8 + r] = rr; rr += cnt8[i*8 + r]; }
      run += dv[j];
    }
  }
}

__global__ __launch_bounds__(256) void k_permute(const int* __restrict__ src,
    const int* __restrict__ dst, const int* __restrict__ et,
    const int* __restrict__ cnt8, int* __restrict__ cur8,
    unsigned* __restrict__ packed, int* __restrict__ dstlist, int E)
{
  int e = blockIdx.x*256 + threadIdx.x;
  if (e >= E) return;
  int d = dst[e], s = src[e], r = et[e];
  int p = atomicAdd(&cur8[d*8 + r], 1);
  unsigned c = (unsigned)cnt8[d*8 + r];
  packed[p] = (unsigned)s | ((unsigned)r << 16) | ((s == d) ? SELFBIT : 0u) | (c << 20);
  dstlist[p] = d;
}

// Fused RGCN: rel-sorted aggregation (2 nodes/wave, 8B gathers) + MFMA S@W
#define NPB 16
__global__ __launch_bounds__(256) void k_rgcn(const unsigned* __restrict__ packed,
    const int* __restrict__ ofs, const int* __restrict__ deg,
    const __hip_bfloat16* __restrict__ xb, const __hip_bfloat16* __restrict__ Wb,
    const float* __restrict__ bias1, __hip_bfloat16* __restrict__ hb, int Nn)
{
  __shared__ short S[NPB * KEXT];   // 36 KB, XOR-swizzled rows
  int t = threadIdx.x, lane = t & 63, wv = t >> 6;
  int half = lane >> 5, sl = lane & 31;
  int n0 = blockIdx.x * NPB;
  char* Sbase = (char*)S;

  for (int i = t; i < NPB*KEXT/8; i += 256) ((uint4*)S)[i] = make_uint4(0,0,0,0);
  __syncthreads();

  // phase 1: each wave handles 2 nodes in parallel (per half), 2 pairs serially
  for (int pi = 0; pi < 2; ++pi) {
    int nl = wv*4 + pi*2 + half;
    int n = n0 + nl;
    char* Sr = Sbase + (long)nl*(KEXT*2);
    unsigned swz = (unsigned)((nl & 7) << 4);
    if (n < Nn) {
      *(uint2*)(Sr + ((2048 + sl*8) ^ swz)) =
          *(const uint2*)&xb[(long)n*128 + sl*4];     // root slab = x row
      int o = ofs[n], dg = deg[n];
      if (dg > 0) {
        float a0=0.f, a1=0.f, a2=0.f, a3=0.f;
        int pr = -1; unsigned lastpk = 1u << 20;
        for (int e0 = 0; e0 < dg; e0 += 8) {
          unsigned pk[8]; uint2 vv[8];
          #pragma unroll
          for (int j = 0; j < 8; ++j) {
            int idx = e0 + j; idx = (idx < dg) ? idx : (dg - 1);
            pk[j] = packed[o + idx];
          }
          #pragma unroll
          for (int j = 0; j < 8; ++j)
            vv[j] = *(const uint2*)&xb[(long)(pk[j] & 0xFFFF)*128 + sl*4];
          #pragma unroll
          for (int j = 0; j < 8; ++j) {
            if (e0 + j < dg) {     // half-uniform
              int r = (pk[j] >> 16) & 7;
              if (r != pr) {       // half-uniform (rel-sorted)
                if (pr >= 0) {
                  float sc = __builtin_amdgcn_rcpf((float)(lastpk >> 20));
                  *(uint2*)(Sr + ((pr*256 + sl*8) ^ swz)) =
                      make_uint2(f2b2(a0*sc, a1*sc), f2b2(a2*sc, a3*sc));
                }
                a0=a1=a2=a3=0.f; pr = r;
              }
              lastpk = pk[j];
              float2 vA = b2f2(vv[j].x), vB = b2f2(vv[j].y);
              a0 += vA.x; a1 += vA.y; a2 += vB.x; a3 += vB.y;
            }
          }
        }
        float sc = __builtin_amdgcn_rcpf((float)(lastpk >> 20));
        *(uint2*)(Sr + ((pr*256 + sl*8) ^ swz)) =
            make_uint2(f2b2(a0*sc, a1*sc), f2b2(a2*sc, a3*sc));
      }
    }
  }
  __syncthreads();

  // phase 2: hb[n0..n0+15][:] = S(16x1152) @ Wb(1152x128) + bias1   (MFMA)
  int col = lane & 15, q = lane >> 4;
  int nt0 = wv*2, nt1 = nt0 + 1;
  const bf16x8* W8 = (const bf16x8*)Wb;
  f32x4 c0 = {0.f,0.f,0.f,0.f}, c1 = {0.f,0.f,0.f,0.f};
  unsigned rswz = (unsigned)((col & 7) << 4);
  for (int ks = 0; ks < KEXT/32; ++ks) {
    bf16x8 a = *(const bf16x8*)(Sbase + (long)col*(KEXT*2)
                                + (((unsigned)(ks*64 + q*16)) ^ rswz));
    bf16x8 b0 = W8[(ks*8 + nt0)*64 + lane];
    bf16x8 b1 = W8[(ks*8 + nt1)*64 + lane];
    c0 = __builtin_amdgcn_mfma_f32_16x16x32_bf16(a, b0, c0, 0, 0, 0);
    c1 = __builtin_amdgcn_mfma_f32_16x16x32_bf16(a, b1, c1, 0, 0, 0);
  }
  #pragma unroll
  for (int r = 0; r < 4; ++r) {
    int row = n0 + q*4 + r;
    if (row < Nn) {
      hb[(long)row*128 + nt0*16 + col] = __float2bfloat16(c0[r] + bias1[nt0*16 + col]);
      hb[(long)row*128 + nt1*16 + col] = __float2bfloat16(c1[r] + bias1[nt1*16 + col]);
    }
  }
}

// xlb = hb @ gatw  (MFMA)
__global__ __launch_bounds__(256) void k_xl(const __hip_bfloat16* __restrict__ hb,
    const __hip_bfloat16* __restrict__ Wg, __hip_bfloat16* __restrict__ xlb, int Nn)
{
  int t = threadIdx.x, lane = t & 63, wv = t >> 6;
  int n0 = blockIdx.x * 16;
  int col = lane & 15, q = lane >> 4;
  int nt0 = wv*2, nt1 = nt0 + 1;
  int arow = n0 + col; if (arow >= Nn) arow = Nn - 1;
  const bf16x8* W8 = (const bf16x8*)Wg;
  f32x4 c0 = {0.f,0.f,0.f,0.f}, c1 = {0.f,0.f,0.f,0.f};
  #pragma unroll
  for (int ks = 0; ks < 4; ++ks) {
    bf16x8 a = *(const bf16x8*)&hb[(long)arow*128 + ks*32 + q*8];
    bf16x8 b0 = W8[(ks*8 + nt0)*64 + lane];
    bf16x8 b1 = W8[(ks*8 + nt1)*64 + lane];
    c0 = __builtin_amdgcn_mfma_f32_16x16x32_bf16(a, b0, c0, 0, 0, 0);
    c1 = __builtin_amdgcn_mfma_f32_16x16x32_bf16(a, b1, c1, 0, 0, 0);
  }
  #pragma unroll
  for (int r = 0; r < 4; ++r) {
    int row = n0 + q*4 + r;
    if (row < Nn) {
      xlb[(long)row*128 + nt0*16 + col] = __float2bfloat16(c0[r]);
      xlb[(long)row*128 + nt1*16 + col] = __float2bfloat16(c1[r]);
    }
  }
}

__global__ __launch_bounds__(256) void k_att(const __hip_bfloat16* __restrict__ xlb,
    const float* __restrict__ attS, const float* __restrict__ attD,
    float* __restrict__ aS, float* __restrict__ aD, int Nn)
{
  int idx = blockIdx.x*256 + threadIdx.x;
  if (idx >= Nn*4) return;
  int n = idx >> 2, hh = idx & 3;
  const __hip_bfloat16* xr = xlb + (long)n*128 + hh*32;
  float s1 = 0.f, s2 = 0.f;
  #pragma unroll
  for (int k = 0; k < 32; k += 2) {
    float2 v = b2f2(*(const unsigned*)&xr[k]);
    s1 += v.x*attS[hh*32+k] + v.y*attS[hh*32+k+1];
    s2 += v.x*attD[hh*32+k] + v.y*attD[hh*32+k+1];
  }
  aS[idx] = s1; aD[idx] = s2;
}

__device__ inline float lrelu(float v){ return v > 0.f ? v : 0.2f*v; }

// per-edge per-head weights (self edges -> 0)
__global__ __launch_bounds__(256) void k_w(const unsigned* __restrict__ packed,
    const int* __restrict__ dstlist, const float* __restrict__ aS,
    const float* __restrict__ aD, float* __restrict__ wgt, int E)
{
  int e = blockIdx.x*256 + threadIdx.x;
  if (e >= E) return;
  unsigned pk = packed[e];
  float4 w;
  if (pk & SELFBIT) {
    w = make_float4(0.f, 0.f, 0.f, 0.f);
  } else {
    int s = pk & 0xFFFF, d = dstlist[e];
    float4 as = *(const float4*)&aS[(long)s*4];
    float4 ad = *(const float4*)&aD[(long)d*4];
    w.x = __expf(lrelu(as.x + ad.x));
    w.y = __expf(lrelu(as.y + ad.y));
    w.z = __expf(lrelu(as.z + ad.z));
    w.w = __expf(lrelu(as.w + ad.w));
  }
  ((float4*)wgt)[e] = w;
}

// GAT accumulate: 2 nodes/wave, streamed weights + 8B xlb gathers
__global__ __launch_bounds__(256) void k_gat(const unsigned* __restrict__ packed,
    const int* __restrict__ ofs, const int* __restrict__ deg,
    const float* __restrict__ wgt, const float* __restrict__ aS,
    const float* __restrict__ aD, const __hip_bfloat16* __restrict__ xlb,
    const float* __restrict__ gatb, float* __restrict__ out, int Nn)
{
  int wvg = (blockIdx.x*256 + threadIdx.x) >> 6;
  int half = (threadIdx.x >> 5) & 1, sl = threadIdx.x & 31;
  int n = wvg*2 + half;
  if (n >= Nn) return;
  int hh = sl >> 3;

  float aSn = aS[(long)n*4 + hh], aDn = aD[(long)n*4 + hh];
  float wself = __expf(lrelu(aSn + aDn));
  float den = wself;
  uint2 xs = *(const uint2*)&xlb[(long)n*128 + sl*4];
  float2 xA = b2f2(xs.x), xB = b2f2(xs.y);
  float acc0 = xA.x*wself, acc1 = xA.y*wself, acc2 = xB.x*wself, acc3 = xB.y*wself;

  int o = ofs[n], dg = deg[n];
  for (int e0 = 0; e0 < dg; e0 += 8) {
    unsigned pk[8]; uint2 vv[8]; float wj[8];
    #pragma unroll
    for (int j = 0; j < 8; ++j) {
      int idx = e0 + j; idx = (idx < dg) ? idx : (dg - 1);
      pk[j] = packed[o + idx];
      wj[j] = wgt[(long)(o + idx)*4 + hh];
    }
    #pragma unroll
    for (int j = 0; j < 8; ++j)
      vv[j] = *(const uint2*)&xlb[(long)(pk[j] & 0xFFFF)*128 + sl*4];
    #pragma unroll
    for (int j = 0; j < 8; ++j) {
      float w = (e0 + j < dg) ? wj[j] : 0.f;   // self edges already 0
      den += w;
      float2 vA = b2f2(vv[j].x), vB = b2f2(vv[j].y);
      acc0 = fmaf(vA.x, w, acc0);
      acc1 = fmaf(vA.y, w, acc1);
      acc2 = fmaf(vB.x, w, acc2);
      acc3 = fmaf(vB.y, w, acc3);
    }
  }
  float rd = 1.f / den;
  float4 gb = *(const float4*)&gatb[sl*4];
  float4 r;
  r.x = acc0*rd + gb.x; r.y = acc1*rd + gb.y;
  r.z = acc2*rd + gb.z; r.w = acc3*rd + gb.w;
  *(float4*)&out[(long)n*128 + sl*4] = r;
}

extern "C" void kernel_launch(void* const* d_in, const int* in_sizes, int n_in,
                              void* d_out, int out_size, void* d_ws, size_t ws_size,
                              hipStream_t stream) {
  const float* x     = (const float*)d_in[0];
  const int*   eidx  = (const int*)  d_in[1];
  const int*   etype = (const int*)  d_in[2];
  const float* comp  = (const float*)d_in[3];
  const float* basis = (const float*)d_in[4];
  const float* root  = (const float*)d_in[5];
  const float* bias1 = (const float*)d_in[6];
  const float* gatw  = (const float*)d_in[7];
  const float* attS  = (const float*)d_in[8];
  const float* attD  = (const float*)d_in[9];
  const float* gatb  = (const float*)d_in[10];

  int Nn = in_sizes[0] / 128;
  int E  = in_sizes[2];
  const int* src = eidx;
  const int* dst = eidx + E;
  int NB1024 = cdiv(Nn, 1024);

  char* ws = (char*)d_ws;
  size_t o = 0;
  __hip_bfloat16* Wb  = (__hip_bfloat16*)(ws + o); o += (size_t)KEXT*128*2;
  __hip_bfloat16* Wg  = (__hip_bfloat16*)(ws + o); o += (size_t)128*128*2;
  __hip_bfloat16* xb  = (__hip_bfloat16*)(ws + o); o += (size_t)Nn*128*2;
  __hip_bfloat16* hb  = (__hip_bfloat16*)(ws + o); o += (size_t)Nn*128*2;
  __hip_bfloat16* xlb = (__hip_bfloat16*)(ws + o); o += (size_t)Nn*128*2;
  float* aS   = (float*)(ws + o); o += (size_t)Nn*4*4;
  float* aD   = (float*)(ws + o); o += (size_t)Nn*4*4;
  int*   deg  = (int*)  (ws + o); o += (size_t)Nn*4;
  int*   ofs  = (int*)  (ws + o); o += (size_t)Nn*4;
  int*   cnt8 = (int*)  (ws + o); o += (size_t)Nn*RREL*4;
  int*   cur8 = (int*)  (ws + o); o += (size_t)Nn*RREL*4;
  int*   bsum = (int*)  (ws + o); o += (size_t)cdiv(Nn,1024)*4 + 64;
  unsigned* packed  = (unsigned*)(ws + o); o += (size_t)E*4;
  int*      dstlist = (int*)     (ws + o); o += (size_t)E*4;
  float*    wgt     = (float*)   (ws + o); o += (size_t)E*4*4;

  float* out = (float*)d_out;

  hipMemsetAsync(deg, 0, (size_t)Nn*4, stream);
  hipMemsetAsync(cnt8, 0, (size_t)Nn*RREL*4, stream);

  k_prep<<<640 + cdiv((long)Nn*16,256), 256, 0, stream>>>(comp, basis, root, gatw, x, Wb, Wg, xb, Nn);
  k_hist<<<cdiv(E,256), 256, 0, stream>>>(dst, etype, deg, cnt8, E);
  k_scanA<<<NB1024, 256, 0, stream>>>(deg, bsum, Nn);
  k_scanB<<<1, 64, 0, stream>>>(bsum, NB1024);
  k_scanC<<<NB1024, 256, 0, stream>>>(deg, bsum, cnt8, ofs, cur8, Nn);
  k_permute<<<cdiv(E,256), 256, 0, stream>>>(src, dst, etype, cnt8, cur8, packed, dstlist, E);

  k_rgcn<<<cdiv(Nn,NPB), 256, 0, stream>>>(packed, ofs, deg, xb, Wb, bias1, hb, Nn);
  k_xl<<<cdiv(Nn,16), 256, 0, stream>>>(hb, Wg, xlb, Nn);
  k_att<<<cdiv((long)Nn*4,256), 256, 0, stream>>>(xlb, attS, attD, aS, aD, Nn);
  k_w<<<cdiv(E,256), 256, 0, stream>>>(packed, dstlist, aS, aD, wgt, E);
  k_gat<<<cdiv((long)Nn*32,256), 256, 0, stream>>>(packed, ofs, deg, wgt, aS, aD, xlb, gatb, out, Nn);
}

// Round 7
// 244.964 us; speedup vs baseline: 15.3623x; 1.1134x over previous
//
#include <hip/hip_runtime.h>
#include <hip/hip_bf16.h>

#define RREL 8
#define NB 20
#define SELFBIT (1u<<19)
#define KEXT 1152   // 1024 rgcn (8 rel x 128) + 128 root

typedef __attribute__((ext_vector_type(8))) short bf16x8;
typedef __attribute__((ext_vector_type(4))) float f32x4;

static inline int cdiv(long a, long b){ return (int)((a + b - 1)/b); }

__device__ inline float2 b2f2(unsigned u){
  union { unsigned u; __hip_bfloat162 b; } c; c.u = u;
  return __bfloat1622float2(c.b);
}
__device__ inline unsigned f2b2(float x, float y){
  float2 f; f.x = x; f.y = y;
  union { unsigned u; __hip_bfloat162 b; } c; c.b = __float22bfloat162_rn(f);
  return c.u;
}

// B-fragment packing for mfma_f32_16x16x32_bf16:
// lane = ((k>>3)&3)*16 + (o&15), elem = k&7, tile (ks = k>>5, nt = o>>4)
__device__ inline long wpack_idx(int k, int o){
  int ks = k >> 5, nt = o >> 4;
  int lane = (((k >> 3) & 3) << 4) | (o & 15);
  return ((long)((ks*8 + nt)*64 + lane))*8 + (k & 7);
}

// merged prep: rel-weights pack + gatw pack + x->bf16 cvt
__global__ __launch_bounds__(256) void k_prep(const float* __restrict__ comp,
    const float* __restrict__ basis, const float* __restrict__ root,
    const float* __restrict__ gatw, const float* __restrict__ x,
    __hip_bfloat16* __restrict__ Wb, __hip_bfloat16* __restrict__ Wg,
    __hip_bfloat16* __restrict__ xb, int Nn)
{
  int bid = blockIdx.x, t = threadIdx.x;
  if (bid < 576) {                      // Wb: KEXT*128 elems
    int idx = bid*256 + t;
    int k = idx >> 7, o = idx & 127;
    float s;
    if (k < 1024) {
      int r = k >> 7, io = ((k & 127) << 7) | o;
      s = 0.f;
      #pragma unroll
      for (int b = 0; b < NB; ++b) s += comp[r*NB + b] * basis[b*16384 + io];
    } else {
      s = root[((k - 1024) << 7) | o];
    }
    Wb[wpack_idx(k, o)] = __float2bfloat16(s);
  } else if (bid < 640) {               // Wg: 128*128
    int idx = (bid - 576)*256 + t;
    int k = idx >> 7, o = idx & 127;
    Wg[wpack_idx(k, o)] = __float2bfloat16(gatw[idx]);
  } else {                              // cvt: Nn*16 groups of 8 floats
    int i = (bid - 640)*256 + t;
    if (i >= Nn*16) return;
    const float4* ip = (const float4*)x;
    float4 f0 = ip[i*2], f1 = ip[i*2+1];
    uint4 o4;
    o4.x = f2b2(f0.x, f0.y); o4.y = f2b2(f0.z, f0.w);
    o4.z = f2b2(f1.x, f1.y); o4.w = f2b2(f1.z, f1.w);
    ((uint4*)xb)[i] = o4;
  }
}

__global__ __launch_bounds__(256) void k_hist(const int* __restrict__ dst,
    const int* __restrict__ et, int* __restrict__ deg, int* __restrict__ cnt8, int E) {
  int e = blockIdx.x*256 + threadIdx.x;
  if (e < E) { int d = dst[e]; atomicAdd(&deg[d], 1); atomicAdd(&cnt8[d*8 + et[e]], 1); }
}

// scan phase A: per-block (1024 nodes) degree sums
__global__ __launch_bounds__(256) void k_scanA(const int* __restrict__ deg,
    int* __restrict__ bsum, int Nn)
{
  __shared__ int wsum[4];
  int b = blockIdx.x, t = threadIdx.x, lane = t & 63, wv = t >> 6;
  int base = b*1024 + t*4;
  int s = 0;
  #pragma unroll
  for (int j = 0; j < 4; ++j) { int i = base + j; if (i < Nn) s += deg[i]; }
  #pragma unroll
  for (int d = 1; d < 64; d <<= 1) s += __shfl_xor(s, d);
  if (lane == 0) wsum[wv] = s;
  __syncthreads();
  if (t == 0) bsum[b] = wsum[0] + wsum[1] + wsum[2] + wsum[3];
}

// scan phase B: exclusive scan of bsum (1 wave)
__global__ __launch_bounds__(64) void k_scanB(int* __restrict__ bsum, int B)
{
  int lane = threadIdx.x & 63;
  int carry = 0;
  for (int c0 = 0; c0 < B; c0 += 64) {
    int i = c0 + lane;
    int v = (i < B) ? bsum[i] : 0;
    int incl = v;
    #pragma unroll
    for (int d = 1; d < 64; d <<= 1) {
      int u = __shfl_up(incl, d);
      if (lane >= d) incl += u;
    }
    int tot = __shfl(incl, 63);
    if (i < B) bsum[i] = carry + incl - v;
    carry += tot;
  }
}

// scan phase C: per-node ofs + per-(node,rel) cur8
__global__ __launch_bounds__(256) void k_scanC(const int* __restrict__ deg,
    const int* __restrict__ bsum, const int* __restrict__ cnt8,
    int* __restrict__ ofs, int* __restrict__ cur8, int Nn)
{
  __shared__ int wsum[5];
  int b = blockIdx.x, t = threadIdx.x, lane = t & 63, wv = t >> 6;
  int base = b*1024 + t*4;
  int dv[4]; int ts = 0;
  #pragma unroll
  for (int j = 0; j < 4; ++j) { int i = base + j; dv[j] = (i < Nn) ? deg[i] : 0; ts += dv[j]; }
  int incl = ts;
  #pragma unroll
  for (int d = 1; d < 64; d <<= 1) {
    int u = __shfl_up(incl, d);
    if (lane >= d) incl += u;
  }
  if (lane == 63) wsum[wv] = incl;
  __syncthreads();
  if (t == 0) {
    int run = 0;
    #pragma unroll
    for (int k = 0; k < 4; ++k) { int s2 = wsum[k]; wsum[k] = run; run += s2; }
  }
  __syncthreads();
  int run = bsum[b] + wsum[wv] + incl - ts;
  #pragma unroll
  for (int j = 0; j < 4; ++j) {
    int i = base + j;
    if (i < Nn) {
      ofs[i] = run;
      int rr = run;
      #pragma unroll
      for (int r = 0; r < 8; ++r) { cur8[i*8 + r] = rr; rr += cnt8[i*8 + r]; }
      run += dv[j];
    }
  }
}

__global__ __launch_bounds__(256) void k_permute(const int* __restrict__ src,
    const int* __restrict__ dst, const int* __restrict__ et,
    const int* __restrict__ cnt8, int* __restrict__ cur8,
    unsigned* __restrict__ packed, int E)
{
  int e = blockIdx.x*256 + threadIdx.x;
  if (e >= E) return;
  int d = dst[e], s = src[e], r = et[e];
  int p = atomicAdd(&cur8[d*8 + r], 1);
  unsigned c = (unsigned)cnt8[d*8 + r];
  packed[p] = (unsigned)s | ((unsigned)r << 16) | ((s == d) ? SELFBIT : 0u) | (c << 20);
}

// Fused RGCN: rel-sorted aggregation (4 nodes/wave, 16 lanes x 16B) + MFMA S@W
#define NPB 16
__global__ __launch_bounds__(256) void k_rgcn(const unsigned* __restrict__ packed,
    const int* __restrict__ ofs, const int* __restrict__ deg,
    const __hip_bfloat16* __restrict__ xb, const __hip_bfloat16* __restrict__ Wb,
    const float* __restrict__ bias1, __hip_bfloat16* __restrict__ hb, int Nn)
{
  __shared__ short S[NPB * KEXT];   // 36 KB, XOR-swizzled rows
  int t = threadIdx.x, lane = t & 63, wv = t >> 6;
  int qt = lane >> 4, ql = lane & 15;   // quarter, lane-in-quarter (8 ch each)
  int n0 = blockIdx.x * NPB;
  char* Sbase = (char*)S;

  for (int i = t; i < NPB*KEXT/8; i += 256) ((uint4*)S)[i] = make_uint4(0,0,0,0);
  __syncthreads();

  // phase 1: each wave aggregates 4 nodes concurrently (one per quarter)
  int nl = wv*4 + qt;
  int n = n0 + nl;
  char* Sr = Sbase + (long)nl*(KEXT*2);
  unsigned swz = (unsigned)((nl & 7) << 4);
  int o = 0, dg = 0;
  if (n < Nn) {
    *(uint4*)(Sr + ((2048u + ql*16) ^ swz)) =
        *(const uint4*)&xb[(long)n*128 + ql*8];       // root slab = x row
    o = ofs[n]; dg = deg[n];
  }
  float a[8] = {};
  int pr = -1; unsigned lastpk = 1u << 20;
  for (int e0 = 0; e0 < dg; e0 += 8) {
    unsigned pk[8]; uint4 vv[8];
    #pragma unroll
    for (int j = 0; j < 8; ++j) {
      int idx = e0 + j; idx = (idx < dg) ? idx : (dg - 1);
      pk[j] = packed[o + idx];
    }
    #pragma unroll
    for (int j = 0; j < 8; ++j)
      vv[j] = *(const uint4*)&xb[(long)(pk[j] & 0xFFFF)*128 + ql*8];
    #pragma unroll
    for (int j = 0; j < 8; ++j) {
      if (e0 + j < dg) {
        int r = (pk[j] >> 16) & 7;
        if (r != pr) {               // rel boundary (edges rel-sorted)
          if (pr >= 0) {
            float sc = __builtin_amdgcn_rcpf((float)(lastpk >> 20));
            uint4 w4;
            w4.x = f2b2(a[0]*sc, a[1]*sc); w4.y = f2b2(a[2]*sc, a[3]*sc);
            w4.z = f2b2(a[4]*sc, a[5]*sc); w4.w = f2b2(a[6]*sc, a[7]*sc);
            *(uint4*)(Sr + (((unsigned)(pr*256 + ql*16)) ^ swz)) = w4;
          }
          #pragma unroll
          for (int c = 0; c < 8; ++c) a[c] = 0.f;
          pr = r;
        }
        lastpk = pk[j];
        float2 v0 = b2f2(vv[j].x), v1 = b2f2(vv[j].y);
        float2 v2 = b2f2(vv[j].z), v3 = b2f2(vv[j].w);
        a[0] += v0.x; a[1] += v0.y; a[2] += v1.x; a[3] += v1.y;
        a[4] += v2.x; a[5] += v2.y; a[6] += v3.x; a[7] += v3.y;
      }
    }
  }
  if (pr >= 0) {
    float sc = __builtin_amdgcn_rcpf((float)(lastpk >> 20));
    uint4 w4;
    w4.x = f2b2(a[0]*sc, a[1]*sc); w4.y = f2b2(a[2]*sc, a[3]*sc);
    w4.z = f2b2(a[4]*sc, a[5]*sc); w4.w = f2b2(a[6]*sc, a[7]*sc);
    *(uint4*)(Sr + (((unsigned)(pr*256 + ql*16)) ^ swz)) = w4;
  }
  __syncthreads();

  // phase 2: hb[n0..n0+15][:] = S(16x1152) @ Wb(1152x128) + bias1   (MFMA)
  int col = lane & 15, q = lane >> 4;
  int nt0 = wv*2, nt1 = nt0 + 1;
  const bf16x8* W8 = (const bf16x8*)Wb;
  f32x4 c0 = {0.f,0.f,0.f,0.f}, c1 = {0.f,0.f,0.f,0.f};
  unsigned rswz = (unsigned)((col & 7) << 4);
  for (int ks = 0; ks < KEXT/32; ++ks) {
    bf16x8 av = *(const bf16x8*)(Sbase + (long)col*(KEXT*2)
                                 + (((unsigned)(ks*64 + q*16)) ^ rswz));
    bf16x8 b0 = W8[(ks*8 + nt0)*64 + lane];
    bf16x8 b1 = W8[(ks*8 + nt1)*64 + lane];
    c0 = __builtin_amdgcn_mfma_f32_16x16x32_bf16(av, b0, c0, 0, 0, 0);
    c1 = __builtin_amdgcn_mfma_f32_16x16x32_bf16(av, b1, c1, 0, 0, 0);
  }
  #pragma unroll
  for (int r = 0; r < 4; ++r) {
    int row = n0 + q*4 + r;
    if (row < Nn) {
      hb[(long)row*128 + nt0*16 + col] = __float2bfloat16(c0[r] + bias1[nt0*16 + col]);
      hb[(long)row*128 + nt1*16 + col] = __float2bfloat16(c1[r] + bias1[nt1*16 + col]);
    }
  }
}

// xlb = hb @ gatw (MFMA) fused with per-node attention dots (head = wv)
__global__ __launch_bounds__(256) void k_xlatt(const __hip_bfloat16* __restrict__ hb,
    const __hip_bfloat16* __restrict__ Wg, const float* __restrict__ attS,
    const float* __restrict__ attD, __hip_bfloat16* __restrict__ xlb,
    float* __restrict__ aS, float* __restrict__ aD, int Nn)
{
  int t = threadIdx.x, lane = t & 63, wv = t >> 6;
  int n0 = blockIdx.x * 16;
  int col = lane & 15, q = lane >> 4;
  int nt0 = wv*2, nt1 = nt0 + 1;
  int arow = n0 + col; if (arow >= Nn) arow = Nn - 1;
  const bf16x8* W8 = (const bf16x8*)Wg;
  f32x4 c0 = {0.f,0.f,0.f,0.f}, c1 = {0.f,0.f,0.f,0.f};
  #pragma unroll
  for (int ks = 0; ks < 4; ++ks) {
    bf16x8 av = *(const bf16x8*)&hb[(long)arow*128 + ks*32 + q*8];
    bf16x8 b0 = W8[(ks*8 + nt0)*64 + lane];
    bf16x8 b1 = W8[(ks*8 + nt1)*64 + lane];
    c0 = __builtin_amdgcn_mfma_f32_16x16x32_bf16(av, b0, c0, 0, 0, 0);
    c1 = __builtin_amdgcn_mfma_f32_16x16x32_bf16(av, b1, c1, 0, 0, 0);
  }
  #pragma unroll
  for (int r = 0; r < 4; ++r) {
    int row = n0 + q*4 + r;
    if (row < Nn) {
      xlb[(long)row*128 + nt0*16 + col] = __float2bfloat16(c0[r]);
      xlb[(long)row*128 + nt1*16 + col] = __float2bfloat16(c1[r]);
    }
  }
  // wave wv owns exactly head wv's 32 columns: cols wv*32 + {col, col+16}
  float s0 = attS[wv*32 + col], s1 = attS[wv*32 + 16 + col];
  float d0 = attD[wv*32 + col], d1 = attD[wv*32 + 16 + col];
  #pragma unroll
  for (int r = 0; r < 4; ++r) {
    float sA = c0[r]*s0 + c1[r]*s1;
    float sD = c0[r]*d0 + c1[r]*d1;
    #pragma unroll
    for (int d = 1; d < 16; d <<= 1) {
      sA += __shfl_xor(sA, d);
      sD += __shfl_xor(sD, d);
    }
    int row = n0 + q*4 + r;
    if (col == 0 && row < Nn) {
      aS[(long)row*4 + wv] = sA;
      aD[(long)row*4 + wv] = sD;
    }
  }
}

__device__ inline float lrelu(float v){ return v > 0.f ? v : 0.2f*v; }

// GAT: 4 nodes/wave (16 lanes x 8ch), fused edge weights, single pass
__global__ __launch_bounds__(256) void k_gat(const unsigned* __restrict__ packed,
    const int* __restrict__ ofs, const int* __restrict__ deg,
    const float* __restrict__ aS, const float* __restrict__ aD,
    const __hip_bfloat16* __restrict__ xlb, const float* __restrict__ gatb,
    float* __restrict__ out, int Nn)
{
  int lane = threadIdx.x & 63;
  int wvg = (blockIdx.x*256 + threadIdx.x) >> 6;
  int qt = lane >> 4, ql = lane & 15;
  int n = wvg*4 + qt;
  int hh = ql >> 2;             // channels 8*ql..8*ql+7 all in head ql>>2
  bool act = (n < Nn);
  int o = 0, dg = 0;
  float aSn = 0.f, aDn = 0.f;
  uint4 xs = make_uint4(0,0,0,0);
  if (act) {
    o = ofs[n]; dg = deg[n];
    aSn = aS[(long)n*4 + hh]; aDn = aD[(long)n*4 + hh];
    xs = *(const uint4*)&xlb[(long)n*128 + ql*8];
  }
  float wself = __expf(lrelu(aSn + aDn));
  float den = wself;
  float2 x0 = b2f2(xs.x), x1 = b2f2(xs.y), x2 = b2f2(xs.z), x3 = b2f2(xs.w);
  float acc[8] = {x0.x*wself, x0.y*wself, x1.x*wself, x1.y*wself,
                  x2.x*wself, x2.y*wself, x3.x*wself, x3.y*wself};

  for (int e0 = 0; e0 < dg; e0 += 8) {
    unsigned pk[8]; uint4 vv[8]; float as_[8];
    #pragma unroll
    for (int j = 0; j < 8; ++j) {
      int idx = e0 + j; idx = (idx < dg) ? idx : (dg - 1);
      pk[j] = packed[o + idx];
    }
    #pragma unroll
    for (int j = 0; j < 8; ++j) {
      int s = pk[j] & 0xFFFF;
      as_[j] = aS[(long)s*4 + hh];
      vv[j]  = *(const uint4*)&xlb[(long)s*128 + ql*8];
    }
    #pragma unroll
    for (int j = 0; j < 8; ++j) {
      bool ok = (e0 + j < dg) && !(pk[j] & SELFBIT);
      float w = __expf(lrelu(as_[j] + aDn));
      w = ok ? w : 0.f;
      den += w;
      float2 v0 = b2f2(vv[j].x), v1 = b2f2(vv[j].y);
      float2 v2 = b2f2(vv[j].z), v3 = b2f2(vv[j].w);
      acc[0] = fmaf(v0.x, w, acc[0]); acc[1] = fmaf(v0.y, w, acc[1]);
      acc[2] = fmaf(v1.x, w, acc[2]); acc[3] = fmaf(v1.y, w, acc[3]);
      acc[4] = fmaf(v2.x, w, acc[4]); acc[5] = fmaf(v2.y, w, acc[5]);
      acc[6] = fmaf(v3.x, w, acc[6]); acc[7] = fmaf(v3.y, w, acc[7]);
    }
  }
  if (act) {
    float rd = 1.f / den;
    float4 g0 = *(const float4*)&gatb[ql*8];
    float4 g1 = *(const float4*)&gatb[ql*8 + 4];
    float4 r0, r1;
    r0.x = acc[0]*rd + g0.x; r0.y = acc[1]*rd + g0.y;
    r0.z = acc[2]*rd + g0.z; r0.w = acc[3]*rd + g0.w;
    r1.x = acc[4]*rd + g1.x; r1.y = acc[5]*rd + g1.y;
    r1.z = acc[6]*rd + g1.z; r1.w = acc[7]*rd + g1.w;
    *(float4*)&out[(long)n*128 + ql*8]     = r0;
    *(float4*)&out[(long)n*128 + ql*8 + 4] = r1;
  }
}

extern "C" void kernel_launch(void* const* d_in, const int* in_sizes, int n_in,
                              void* d_out, int out_size, void* d_ws, size_t ws_size,
                              hipStream_t stream) {
  const float* x     = (const float*)d_in[0];
  const int*   eidx  = (const int*)  d_in[1];
  const int*   etype = (const int*)  d_in[2];
  const float* comp  = (const float*)d_in[3];
  const float* basis = (const float*)d_in[4];
  const float* root  = (const float*)d_in[5];
  const float* bias1 = (const float*)d_in[6];
  const float* gatw  = (const float*)d_in[7];
  const float* attS  = (const float*)d_in[8];
  const float* attD  = (const float*)d_in[9];
  const float* gatb  = (const float*)d_in[10];

  int Nn = in_sizes[0] / 128;
  int E  = in_sizes[2];
  const int* src = eidx;
  const int* dst = eidx + E;
  int NB1024 = cdiv(Nn, 1024);

  char* ws = (char*)d_ws;
  size_t o = 0;
  __hip_bfloat16* Wb  = (__hip_bfloat16*)(ws + o); o += (size_t)KEXT*128*2;
  __hip_bfloat16* Wg  = (__hip_bfloat16*)(ws + o); o += (size_t)128*128*2;
  __hip_bfloat16* xb  = (__hip_bfloat16*)(ws + o); o += (size_t)Nn*128*2;
  __hip_bfloat16* hb  = (__hip_bfloat16*)(ws + o); o += (size_t)Nn*128*2;
  __hip_bfloat16* xlb = (__hip_bfloat16*)(ws + o); o += (size_t)Nn*128*2;
  float* aS   = (float*)(ws + o); o += (size_t)Nn*4*4;
  float* aD   = (float*)(ws + o); o += (size_t)Nn*4*4;
  int*   deg  = (int*)  (ws + o); o += (size_t)Nn*4;
  int*   ofs  = (int*)  (ws + o); o += (size_t)Nn*4;
  int*   cnt8 = (int*)  (ws + o); o += (size_t)Nn*RREL*4;
  int*   cur8 = (int*)  (ws + o); o += (size_t)Nn*RREL*4;
  int*   bsum = (int*)  (ws + o); o += (size_t)cdiv(Nn,1024)*4 + 64;
  unsigned* packed = (unsigned*)(ws + o); o += (size_t)E*4;

  float* out = (float*)d_out;

  hipMemsetAsync(deg, 0, (size_t)Nn*4, stream);
  hipMemsetAsync(cnt8, 0, (size_t)Nn*RREL*4, stream);

  k_prep<<<640 + cdiv((long)Nn*16,256), 256, 0, stream>>>(comp, basis, root, gatw, x, Wb, Wg, xb, Nn);
  k_hist<<<cdiv(E,256), 256, 0, stream>>>(dst, etype, deg, cnt8, E);
  k_scanA<<<NB1024, 256, 0, stream>>>(deg, bsum, Nn);
  k_scanB<<<1, 64, 0, stream>>>(bsum, NB1024);
  k_scanC<<<NB1024, 256, 0, stream>>>(deg, bsum, cnt8, ofs, cur8, Nn);
  k_permute<<<cdiv(E,256), 256, 0, stream>>>(src, dst, etype, cnt8, cur8, packed, E);

  k_rgcn<<<cdiv(Nn,NPB), 256, 0, stream>>>(packed, ofs, deg, xb, Wb, bias1, hb, Nn);
  k_xlatt<<<cdiv(Nn,16), 256, 0, stream>>>(hb, Wg, attS, attD, xlb, aS, aD, Nn);
  k_gat<<<cdiv((long)Nn*16,256), 256, 0, stream>>>(packed, ofs, deg, aS, aD, xlb, gatb, out, Nn);
}

// Round 8
// 216.295 us; speedup vs baseline: 17.3985x; 1.1325x over previous
//
#include <hip/hip_runtime.h>
#include <hip/hip_bf16.h>

#define RREL 8
#define NB 20
#define SELFBIT (1u<<19)
#define KEXT 1152   // 1024 rgcn (8 rel x 128) + 128 root

typedef __attribute__((ext_vector_type(8))) short bf16x8;
typedef __attribute__((ext_vector_type(4))) float f32x4;

static inline int cdiv(long a, long b){ return (int)((a + b - 1)/b); }

__device__ inline float2 b2f2(unsigned u){
  union { unsigned u; __hip_bfloat162 b; } c; c.u = u;
  return __bfloat1622float2(c.b);
}
__device__ inline unsigned f2b2(float x, float y){
  float2 f; f.x = x; f.y = y;
  union { unsigned u; __hip_bfloat162 b; } c; c.b = __float22bfloat162_rn(f);
  return c.u;
}
__device__ inline int sum16(unsigned long long u){
  return (int)((u & 0xFFFFull) + ((u>>16) & 0xFFFFull)
             + ((u>>32) & 0xFFFFull) + ((u>>48) & 0xFFFFull));
}

// B-fragment packing for mfma_f32_16x16x32_bf16:
// lane = ((k>>3)&3)*16 + (o&15), elem = k&7, tile (ks = k>>5, nt = o>>4)
__device__ inline long wpack_idx(int k, int o){
  int ks = k >> 5, nt = o >> 4;
  int lane = (((k >> 3) & 3) << 4) | (o & 15);
  return ((long)((ks*8 + nt)*64 + lane))*8 + (k & 7);
}

// merged prep: rel-weights pack + gatw pack + x->bf16 cvt + edge histogram
__global__ __launch_bounds__(256) void k_prep(const float* __restrict__ comp,
    const float* __restrict__ basis, const float* __restrict__ root,
    const float* __restrict__ gatw, const float* __restrict__ x,
    const int* __restrict__ dst, const int* __restrict__ et,
    __hip_bfloat16* __restrict__ Wb, __hip_bfloat16* __restrict__ Wg,
    __hip_bfloat16* __restrict__ xb, unsigned long long* __restrict__ hist2,
    int Nn, int E)
{
  int bid = blockIdx.x, t = threadIdx.x;
  int cvtB = (Nn*16 + 255) >> 8;
  if (bid < 576) {                      // Wb: KEXT*128 elems
    int idx = bid*256 + t;
    int k = idx >> 7, o = idx & 127;
    float s;
    if (k < 1024) {
      int r = k >> 7, io = ((k & 127) << 7) | o;
      s = 0.f;
      #pragma unroll
      for (int b = 0; b < NB; ++b) s += comp[r*NB + b] * basis[b*16384 + io];
    } else {
      s = root[((k - 1024) << 7) | o];
    }
    Wb[wpack_idx(k, o)] = __float2bfloat16(s);
  } else if (bid < 640) {               // Wg: 128*128
    int idx = (bid - 576)*256 + t;
    int k = idx >> 7, o = idx & 127;
    Wg[wpack_idx(k, o)] = __float2bfloat16(gatw[idx]);
  } else if (bid < 640 + cvtB) {        // cvt: Nn*16 groups of 8 floats
    int i = (bid - 640)*256 + t;
    if (i >= Nn*16) return;
    const float4* ip = (const float4*)x;
    float4 f0 = ip[i*2], f1 = ip[i*2+1];
    uint4 o4;
    o4.x = f2b2(f0.x, f0.y); o4.y = f2b2(f0.z, f0.w);
    o4.z = f2b2(f1.x, f1.y); o4.w = f2b2(f1.z, f1.w);
    ((uint4*)xb)[i] = o4;
  } else {                              // histogram: 4 edges/thread
    int e0 = (bid - 640 - cvtB)*1024 + t*4;
    if (e0 >= E) return;
    if (e0 + 3 < E) {
      int4 d4 = *(const int4*)&dst[e0];
      int4 r4 = *(const int4*)&et[e0];
      atomicAdd(&hist2[(long)d4.x*2 + (r4.x>>2)], 1ull << ((r4.x&3)*16));
      atomicAdd(&hist2[(long)d4.y*2 + (r4.y>>2)], 1ull << ((r4.y&3)*16));
      atomicAdd(&hist2[(long)d4.z*2 + (r4.z>>2)], 1ull << ((r4.z&3)*16));
      atomicAdd(&hist2[(long)d4.w*2 + (r4.w>>2)], 1ull << ((r4.w&3)*16));
    } else {
      for (int j = 0; j < 4 && e0 + j < E; ++j) {
        int d = dst[e0+j], r = et[e0+j];
        atomicAdd(&hist2[(long)d*2 + (r>>2)], 1ull << ((r&3)*16));
      }
    }
  }
}

// scan phase A: per-block (1024 nodes) degree sums from hist2
__global__ __launch_bounds__(256) void k_scanA(const unsigned long long* __restrict__ hist2,
    int* __restrict__ bsum, int Nn)
{
  __shared__ int wsum[4];
  int b = blockIdx.x, t = threadIdx.x, lane = t & 63, wv = t >> 6;
  int base = b*1024 + t*4;
  int s = 0;
  #pragma unroll
  for (int j = 0; j < 4; ++j) {
    int i = base + j;
    if (i < Nn) s += sum16(hist2[(long)i*2]) + sum16(hist2[(long)i*2+1]);
  }
  #pragma unroll
  for (int d = 1; d < 64; d <<= 1) s += __shfl_xor(s, d);
  if (lane == 0) wsum[wv] = s;
  __syncthreads();
  if (t == 0) bsum[b] = wsum[0] + wsum[1] + wsum[2] + wsum[3];
}

// scan phase C: block base (inline reduce of bsum) + per-node ofs/deg/cur8
__global__ __launch_bounds__(256) void k_scanC(const unsigned long long* __restrict__ hist2,
    const int* __restrict__ bsum, int* __restrict__ ofs, int* __restrict__ deg,
    int* __restrict__ cur8, int Nn)
{
  __shared__ int wsum[5];
  __shared__ int sbase;
  int b = blockIdx.x, t = threadIdx.x, lane = t & 63, wv = t >> 6;
  if (wv == 0) {                 // wave 0: base = sum of bsum[0..b-1]
    int s = 0;
    for (int i = lane; i < b; i += 64) s += bsum[i];
    #pragma unroll
    for (int d = 1; d < 64; d <<= 1) s += __shfl_xor(s, d);
    if (lane == 0) sbase = s;
  }
  int base = b*1024 + t*4;
  int dv[4], c8[4][8]; int ts = 0;
  #pragma unroll
  for (int j = 0; j < 4; ++j) {
    int i = base + j;
    int dsum = 0;
    if (i < Nn) {
      unsigned long long u0 = hist2[(long)i*2], u1 = hist2[(long)i*2+1];
      #pragma unroll
      for (int r = 0; r < 4; ++r) {
        c8[j][r]   = (int)((u0 >> (r*16)) & 0xFFFFull);
        c8[j][r+4] = (int)((u1 >> (r*16)) & 0xFFFFull);
        dsum += c8[j][r] + c8[j][r+4];
      }
    }
    dv[j] = (i < Nn) ? dsum : 0;
    ts += dv[j];
  }
  int incl = ts;
  #pragma unroll
  for (int d = 1; d < 64; d <<= 1) {
    int u = __shfl_up(incl, d);
    if (lane >= d) incl += u;
  }
  if (lane == 63) wsum[wv] = incl;
  __syncthreads();
  if (t == 0) {
    int run = 0;
    #pragma unroll
    for (int k = 0; k < 4; ++k) { int s2 = wsum[k]; wsum[k] = run; run += s2; }
  }
  __syncthreads();
  int run = sbase + wsum[wv] + incl - ts;
  #pragma unroll
  for (int j = 0; j < 4; ++j) {
    int i = base + j;
    if (i < Nn) {
      ofs[i] = run; deg[i] = dv[j];
      int rr = run;
      #pragma unroll
      for (int r = 0; r < 8; ++r) { cur8[i*8 + r] = rr; rr += c8[j][r]; }
      run += dv[j];
    }
  }
}

__global__ __launch_bounds__(256) void k_permute(const int* __restrict__ src,
    const int* __restrict__ dst, const int* __restrict__ et,
    int* __restrict__ cur8, unsigned* __restrict__ packed, int E)
{
  int e = blockIdx.x*256 + threadIdx.x;
  if (e >= E) return;
  int d = dst[e], s = src[e], r = et[e];
  int p = atomicAdd(&cur8[d*8 + r], 1);
  packed[p] = (unsigned)s | ((unsigned)r << 16) | ((s == d) ? SELFBIT : 0u);
}

// Fused RGCN: rel-sorted aggregation (4 nodes/wave, 16 lanes x 16B) + MFMA S@W
#define NPB 16
__global__ __launch_bounds__(256) void k_rgcn(const unsigned* __restrict__ packed,
    const int* __restrict__ ofs, const int* __restrict__ deg,
    const __hip_bfloat16* __restrict__ xb, const __hip_bfloat16* __restrict__ Wb,
    const float* __restrict__ bias1, __hip_bfloat16* __restrict__ hb, int Nn)
{
  __shared__ short S[NPB * KEXT];   // 36 KB, XOR-swizzled rows
  int t = threadIdx.x, lane = t & 63, wv = t >> 6;
  int qt = lane >> 4, ql = lane & 15;   // quarter, lane-in-quarter (8 ch each)
  int n0 = blockIdx.x * NPB;
  char* Sbase = (char*)S;

  for (int i = t; i < NPB*KEXT/8; i += 256) ((uint4*)S)[i] = make_uint4(0,0,0,0);
  __syncthreads();

  // phase 1: each wave aggregates 4 nodes concurrently (one per quarter)
  int nl = wv*4 + qt;
  int n = n0 + nl;
  char* Sr = Sbase + (long)nl*(KEXT*2);
  unsigned swz = (unsigned)((nl & 7) << 4);
  int o = 0, dg = 0;
  if (n < Nn) {
    *(uint4*)(Sr + ((2048u + ql*16) ^ swz)) =
        *(const uint4*)&xb[(long)n*128 + ql*8];       // root slab = x row
    o = ofs[n]; dg = deg[n];
  }
  float a[8] = {};
  int pr = -1, rc = 0;
  for (int e0 = 0; e0 < dg; e0 += 8) {
    unsigned pk[8]; uint4 vv[8];
    #pragma unroll
    for (int j = 0; j < 8; ++j) {
      int idx = e0 + j; idx = (idx < dg) ? idx : (dg - 1);
      pk[j] = packed[o + idx];
    }
    #pragma unroll
    for (int j = 0; j < 8; ++j)
      vv[j] = *(const uint4*)&xb[(long)(pk[j] & 0xFFFF)*128 + ql*8];
    #pragma unroll
    for (int j = 0; j < 8; ++j) {
      if (e0 + j < dg) {
        int r = (pk[j] >> 16) & 7;
        if (r != pr) {               // rel boundary (edges rel-sorted)
          if (pr >= 0) {
            float sc = __builtin_amdgcn_rcpf((float)rc);
            uint4 w4;
            w4.x = f2b2(a[0]*sc, a[1]*sc); w4.y = f2b2(a[2]*sc, a[3]*sc);
            w4.z = f2b2(a[4]*sc, a[5]*sc); w4.w = f2b2(a[6]*sc, a[7]*sc);
            *(uint4*)(Sr + (((unsigned)(pr*256 + ql*16)) ^ swz)) = w4;
          }
          #pragma unroll
          for (int c = 0; c < 8; ++c) a[c] = 0.f;
          pr = r; rc = 0;
        }
        rc++;
        float2 v0 = b2f2(vv[j].x), v1 = b2f2(vv[j].y);
        float2 v2 = b2f2(vv[j].z), v3 = b2f2(vv[j].w);
        a[0] += v0.x; a[1] += v0.y; a[2] += v1.x; a[3] += v1.y;
        a[4] += v2.x; a[5] += v2.y; a[6] += v3.x; a[7] += v3.y;
      }
    }
  }
  if (pr >= 0) {
    float sc = __builtin_amdgcn_rcpf((float)rc);
    uint4 w4;
    w4.x = f2b2(a[0]*sc, a[1]*sc); w4.y = f2b2(a[2]*sc, a[3]*sc);
    w4.z = f2b2(a[4]*sc, a[5]*sc); w4.w = f2b2(a[6]*sc, a[7]*sc);
    *(uint4*)(Sr + (((unsigned)(pr*256 + ql*16)) ^ swz)) = w4;
  }
  __syncthreads();

  // phase 2: hb[n0..n0+15][:] = S(16x1152) @ Wb(1152x128) + bias1   (MFMA)
  int col = lane & 15, q = lane >> 4;
  int nt0 = wv*2, nt1 = nt0 + 1;
  const bf16x8* W8 = (const bf16x8*)Wb;
  f32x4 c0 = {0.f,0.f,0.f,0.f}, c1 = {0.f,0.f,0.f,0.f};
  unsigned rswz = (unsigned)((col & 7) << 4);
  for (int ks = 0; ks < KEXT/32; ++ks) {
    bf16x8 av = *(const bf16x8*)(Sbase + (long)col*(KEXT*2)
                                 + (((unsigned)(ks*64 + q*16)) ^ rswz));
    bf16x8 b0 = W8[(ks*8 + nt0)*64 + lane];
    bf16x8 b1 = W8[(ks*8 + nt1)*64 + lane];
    c0 = __builtin_amdgcn_mfma_f32_16x16x32_bf16(av, b0, c0, 0, 0, 0);
    c1 = __builtin_amdgcn_mfma_f32_16x16x32_bf16(av, b1, c1, 0, 0, 0);
  }
  #pragma unroll
  for (int r = 0; r < 4; ++r) {
    int row = n0 + q*4 + r;
    if (row < Nn) {
      hb[(long)row*128 + nt0*16 + col] = __float2bfloat16(c0[r] + bias1[nt0*16 + col]);
      hb[(long)row*128 + nt1*16 + col] = __float2bfloat16(c1[r] + bias1[nt1*16 + col]);
    }
  }
}

// xlb = hb @ gatw (MFMA) fused with per-node attention dots (head = wv)
__global__ __launch_bounds__(256) void k_xlatt(const __hip_bfloat16* __restrict__ hb,
    const __hip_bfloat16* __restrict__ Wg, const float* __restrict__ attS,
    const float* __restrict__ attD, __hip_bfloat16* __restrict__ xlb,
    float* __restrict__ aS, float* __restrict__ aD, int Nn)
{
  int t = threadIdx.x, lane = t & 63, wv = t >> 6;
  int n0 = blockIdx.x * 16;
  int col = lane & 15, q = lane >> 4;
  int nt0 = wv*2, nt1 = nt0 + 1;
  int arow = n0 + col; if (arow >= Nn) arow = Nn - 1;
  const bf16x8* W8 = (const bf16x8*)Wg;
  f32x4 c0 = {0.f,0.f,0.f,0.f}, c1 = {0.f,0.f,0.f,0.f};
  #pragma unroll
  for (int ks = 0; ks < 4; ++ks) {
    bf16x8 av = *(const bf16x8*)&hb[(long)arow*128 + ks*32 + q*8];
    bf16x8 b0 = W8[(ks*8 + nt0)*64 + lane];
    bf16x8 b1 = W8[(ks*8 + nt1)*64 + lane];
    c0 = __builtin_amdgcn_mfma_f32_16x16x32_bf16(av, b0, c0, 0, 0, 0);
    c1 = __builtin_amdgcn_mfma_f32_16x16x32_bf16(av, b1, c1, 0, 0, 0);
  }
  #pragma unroll
  for (int r = 0; r < 4; ++r) {
    int row = n0 + q*4 + r;
    if (row < Nn) {
      xlb[(long)row*128 + nt0*16 + col] = __float2bfloat16(c0[r]);
      xlb[(long)row*128 + nt1*16 + col] = __float2bfloat16(c1[r]);
    }
  }
  // wave wv owns exactly head wv's 32 columns: cols wv*32 + {col, col+16}
  float s0 = attS[wv*32 + col], s1 = attS[wv*32 + 16 + col];
  float d0 = attD[wv*32 + col], d1 = attD[wv*32 + 16 + col];
  #pragma unroll
  for (int r = 0; r < 4; ++r) {
    float sA = c0[r]*s0 + c1[r]*s1;
    float sD = c0[r]*d0 + c1[r]*d1;
    #pragma unroll
    for (int d = 1; d < 16; d <<= 1) {
      sA += __shfl_xor(sA, d);
      sD += __shfl_xor(sD, d);
    }
    int row = n0 + q*4 + r;
    if (col == 0 && row < Nn) {
      aS[(long)row*4 + wv] = sA;
      aD[(long)row*4 + wv] = sD;
    }
  }
}

__device__ inline float lrelu(float v){ return v > 0.f ? v : 0.2f*v; }

// GAT: 4 nodes/wave (16 lanes x 8ch), fused edge weights, single pass
__global__ __launch_bounds__(256) void k_gat(const unsigned* __restrict__ packed,
    const int* __restrict__ ofs, const int* __restrict__ deg,
    const float* __restrict__ aS, const float* __restrict__ aD,
    const __hip_bfloat16* __restrict__ xlb, const float* __restrict__ gatb,
    float* __restrict__ out, int Nn)
{
  int lane = threadIdx.x & 63;
  int wvg = (blockIdx.x*256 + threadIdx.x) >> 6;
  int qt = lane >> 4, ql = lane & 15;
  int n = wvg*4 + qt;
  int hh = ql >> 2;             // channels 8*ql..8*ql+7 all in head ql>>2
  bool act = (n < Nn);
  int o = 0, dg = 0;
  float aSn = 0.f, aDn = 0.f;
  uint4 xs = make_uint4(0,0,0,0);
  if (act) {
    o = ofs[n]; dg = deg[n];
    aSn = aS[(long)n*4 + hh]; aDn = aD[(long)n*4 + hh];
    xs = *(const uint4*)&xlb[(long)n*128 + ql*8];
  }
  float wself = __expf(lrelu(aSn + aDn));
  float den = wself;
  float2 x0 = b2f2(xs.x), x1 = b2f2(xs.y), x2 = b2f2(xs.z), x3 = b2f2(xs.w);
  float acc[8] = {x0.x*wself, x0.y*wself, x1.x*wself, x1.y*wself,
                  x2.x*wself, x2.y*wself, x3.x*wself, x3.y*wself};

  for (int e0 = 0; e0 < dg; e0 += 8) {
    unsigned pk[8]; uint4 vv[8]; float as_[8];
    #pragma unroll
    for (int j = 0; j < 8; ++j) {
      int idx = e0 + j; idx = (idx < dg) ? idx : (dg - 1);
      pk[j] = packed[o + idx];
    }
    #pragma unroll
    for (int j = 0; j < 8; ++j) {
      int s = pk[j] & 0xFFFF;
      as_[j] = aS[(long)s*4 + hh];
      vv[j]  = *(const uint4*)&xlb[(long)s*128 + ql*8];
    }
    #pragma unroll
    for (int j = 0; j < 8; ++j) {
      bool ok = (e0 + j < dg) && !(pk[j] & SELFBIT);
      float w = __expf(lrelu(as_[j] + aDn));
      w = ok ? w : 0.f;
      den += w;
      float2 v0 = b2f2(vv[j].x), v1 = b2f2(vv[j].y);
      float2 v2 = b2f2(vv[j].z), v3 = b2f2(vv[j].w);
      acc[0] = fmaf(v0.x, w, acc[0]); acc[1] = fmaf(v0.y, w, acc[1]);
      acc[2] = fmaf(v1.x, w, acc[2]); acc[3] = fmaf(v1.y, w, acc[3]);
      acc[4] = fmaf(v2.x, w, acc[4]); acc[5] = fmaf(v2.y, w, acc[5]);
      acc[6] = fmaf(v3.x, w, acc[6]); acc[7] = fmaf(v3.y, w, acc[7]);
    }
  }
  if (act) {
    float rd = 1.f / den;
    float4 g0 = *(const float4*)&gatb[ql*8];
    float4 g1 = *(const float4*)&gatb[ql*8 + 4];
    float4 r0, r1;
    r0.x = acc[0]*rd + g0.x; r0.y = acc[1]*rd + g0.y;
    r0.z = acc[2]*rd + g0.z; r0.w = acc[3]*rd + g0.w;
    r1.x = acc[4]*rd + g1.x; r1.y = acc[5]*rd + g1.y;
    r1.z = acc[6]*rd + g1.z; r1.w = acc[7]*rd + g1.w;
    *(float4*)&out[(long)n*128 + ql*8]     = r0;
    *(float4*)&out[(long)n*128 + ql*8 + 4] = r1;
  }
}

extern "C" void kernel_launch(void* const* d_in, const int* in_sizes, int n_in,
                              void* d_out, int out_size, void* d_ws, size_t ws_size,
                              hipStream_t stream) {
  const float* x     = (const float*)d_in[0];
  const int*   eidx  = (const int*)  d_in[1];
  const int*   etype = (const int*)  d_in[2];
  const float* comp  = (const float*)d_in[3];
  const float* basis = (const float*)d_in[4];
  const float* root  = (const float*)d_in[5];
  const float* bias1 = (const float*)d_in[6];
  const float* gatw  = (const float*)d_in[7];
  const float* attS  = (const float*)d_in[8];
  const float* attD  = (const float*)d_in[9];
  const float* gatb  = (const float*)d_in[10];

  int Nn = in_sizes[0] / 128;
  int E  = in_sizes[2];
  const int* src = eidx;
  const int* dst = eidx + E;
  int NB1024 = cdiv(Nn, 1024);

  char* ws = (char*)d_ws;
  size_t o = 0;
  auto alloc = [&](size_t bytes) { void* p = ws + o; o = (o + bytes + 255) & ~(size_t)255; return p; };
  __hip_bfloat16* Wb  = (__hip_bfloat16*)alloc((size_t)KEXT*128*2);
  __hip_bfloat16* Wg  = (__hip_bfloat16*)alloc((size_t)128*128*2);
  __hip_bfloat16* xb  = (__hip_bfloat16*)alloc((size_t)Nn*128*2);
  __hip_bfloat16* hb  = (__hip_bfloat16*)alloc((size_t)Nn*128*2);
  __hip_bfloat16* xlb = (__hip_bfloat16*)alloc((size_t)Nn*128*2);
  float* aS   = (float*)alloc((size_t)Nn*4*4);
  float* aD   = (float*)alloc((size_t)Nn*4*4);
  int*   deg  = (int*)  alloc((size_t)Nn*4);
  int*   ofs  = (int*)  alloc((size_t)Nn*4);
  int*   cur8 = (int*)  alloc((size_t)Nn*RREL*4);
  int*   bsum = (int*)  alloc((size_t)NB1024*4);
  unsigned long long* hist2 = (unsigned long long*)alloc((size_t)Nn*16);
  unsigned* packed = (unsigned*)alloc((size_t)E*4);

  float* out = (float*)d_out;

  hipMemsetAsync(hist2, 0, (size_t)Nn*16, stream);

  int cvtB = cdiv((long)Nn*16, 256);
  int histB = cdiv(E, 1024);
  k_prep<<<640 + cvtB + histB, 256, 0, stream>>>(comp, basis, root, gatw, x,
                                                 dst, etype, Wb, Wg, xb, hist2, Nn, E);
  k_scanA<<<NB1024, 256, 0, stream>>>(hist2, bsum, Nn);
  k_scanC<<<NB1024, 256, 0, stream>>>(hist2, bsum, ofs, deg, cur8, Nn);
  k_permute<<<cdiv(E,256), 256, 0, stream>>>(src, dst, etype, cur8, packed, E);

  k_rgcn<<<cdiv(Nn,NPB), 256, 0, stream>>>(packed, ofs, deg, xb, Wb, bias1, hb, Nn);
  k_xlatt<<<cdiv(Nn,16), 256, 0, stream>>>(hb, Wg, attS, attD, xlb, aS, aD, Nn);
  k_gat<<<cdiv((long)Nn*16,256), 256, 0, stream>>>(packed, ofs, deg, aS, aD, xlb, gatb, out, Nn);
}